// Round 19
// baseline (811.619 us; speedup 1.0000x reference)
//
#include <hip/hip_runtime.h>
#include <hip/hip_bf16.h>

#define N_NODES 2500
#define N_EDGES 50000
#define C 128
#define MC 19
#define RSTR 20
#define NL 4
#define NB 600
#define GW 10
#define NTAP (2*GW+1)
#define NBUK 4
#define BUKW 625
#define N4 (N_NODES*NBUK)
#define ASTR 136   // bf16 LDS row stride (128 + 8 pad)
#define MSTR 132   // f32 msum row stride (128 + 4 pad)
#define MAXE 96    // per-node edge cap in k_attn
#define EB 64      // edges per k_efeat/k_rad block
#define NQKB ((N_NODES+31)/32)   // 79
#define NRADB ((N_EDGES+EB-1)/EB) // 782

typedef float floatx2 __attribute__((ext_vector_type(2)));
typedef short bf16x8 __attribute__((ext_vector_type(8)));
typedef float f32x4 __attribute__((ext_vector_type(4)));

__device__ __forceinline__ float silu(float v){ return v / (1.f + __expf(-v)); }
__device__ __forceinline__ int l_of_m(int m){
  return (m==0)?0 : (m<4)?1 : (m<9)?2 : (m<14)?3 : 4;
}
__device__ __forceinline__ unsigned pack2(float a, float b){
  __hip_bfloat162 h2;
  h2.x = __float2bfloat16(a);
  h2.y = __float2bfloat16(b);
  return *(unsigned*)&h2;
}
__device__ __forceinline__ unsigned short bf16of(float v){
  __hip_bfloat16 h = __float2bfloat16(v);
  return *(unsigned short*)&h;
}
__device__ __forceinline__ float bf2f(unsigned short u){
  return __uint_as_float(((unsigned)u) << 16);
}
__device__ __forceinline__ float2 bf2f2(unsigned u){
  float2 r;
  r.x = __uint_as_float(u << 16);
  r.y = __uint_as_float(u & 0xffff0000u);
  return r;
}
__device__ __forceinline__ bf16x8 packbf8(float4 a, float4 b){
  union { unsigned u[4]; bf16x8 v; } r;
  r.u[0] = pack2(a.x, a.y); r.u[1] = pack2(a.z, a.w);
  r.u[2] = pack2(b.x, b.y); r.u[3] = pack2(b.z, b.w);
  return r.v;
}
// pack 2 f32 -> 2 fp8 e4m3 (low 16 bits); values pre-clamped to +-448
__device__ __forceinline__ unsigned short packfp8(float a, float b){
  float ac = fminf(fmaxf(a, -448.f), 448.f);
  float bc = fminf(fmaxf(b, -448.f), 448.f);
  return (unsigned short)((unsigned)__builtin_amdgcn_cvt_pk_fp8_f32(ac, bc, 0, false) & 0xffffu);
}

// ---------------- weight pre-pack: transposed bf16 copies in workspace (L2-resident) ----------------
__global__ __launch_bounds__(256) void k_packall(
    const float* __restrict__ We2, const float* __restrict__ Wv, const float* __restrict__ Wo,
    const float* __restrict__ W1, const float* __restrict__ W2,
    const float* __restrict__ Wq, const float* __restrict__ Wk,
    const float* __restrict__ We1,
    unsigned short* we2t, unsigned short* wvt, unsigned short* wot,
    unsigned short* w1t, unsigned short* w2t, unsigned short* wqt, unsigned short* wkt,
    unsigned short* we1b){
  unsigned id = blockIdx.x*256 + threadIdx.x;   // pair index
  const unsigned PERL = 98304u;                  // pairs per layer
  if (id < 8192u){
    unsigned f = id & 127u, cp = id >> 7;
    *(unsigned*)&we2t[f*C + 2*cp] = pack2(We2[(2*cp)*C + f], We2[(2*cp+1)*C + f]);
    return;
  }
  unsigned rem = id - 8192u;
  unsigned layer = rem / PERL;
  if (layer >= 4u){
    unsigned r5 = rem - 4u*PERL;
    if (r5 < 38400u){
      unsigned r = r5 >> 6, cp = r5 & 63u;
      *(unsigned*)&we1b[r*C + 2*cp] = pack2(We1[(size_t)r*C + 2*cp], We1[(size_t)r*C + 2*cp + 1]);
    }
    return;
  }
  unsigned r2 = rem - layer*PERL;
  if (r2 < 32768u){
    unsigned mi = r2 >> 13;          // 0:Wv 1:Wo 2:W1 3:W2
    unsigned p = r2 & 8191u;
    unsigned f = p & 127u, cp = p >> 7;
    const float* S; unsigned short* D;
    if (mi==0){ S = Wv + (size_t)layer*C*C; D = wvt + (size_t)layer*16384; }
    else if (mi==1){ S = Wo + (size_t)layer*C*C; D = wot + (size_t)layer*16384; }
    else if (mi==2){ S = W1 + (size_t)layer*C*C; D = w1t + (size_t)layer*16384; }
    else { S = W2 + (size_t)layer*C*C; D = w2t + (size_t)layer*16384; }
    *(unsigned*)&D[f*C + 2*cp] = pack2(S[(2*cp)*C + f], S[(2*cp+1)*C + f]);
  } else {
    unsigned r3 = r2 - 32768u;       // 0..65535
    unsigned mi = r3 >> 15;          // 0: Wq, 1: Wk
    unsigned p = r3 & 32767u;
    unsigned f = p & 511u, cp = p >> 9;
    const float* S = (mi==0 ? Wq : Wk) + (size_t)layer*C*512;
    unsigned short* D = (mi==0 ? wqt : wkt) + (size_t)layer*65536;
    *(unsigned*)&D[(size_t)f*C + 2*cp] = pack2(S[(size_t)(2*cp)*512 + f], S[(size_t)(2*cp+1)*512 + f]);
  }
}

// ---------------- CSR build (bucketed by src-range) ----------------
__global__ void k_count(const int* tgt, const int* src, int* deg){
  int e = blockIdx.x*256 + threadIdx.x;
  if (e < N_EDGES){
    int b = (unsigned)src[e] / BUKW;
    atomicAdd(&deg[tgt[e]*NBUK + b], 1);
  }
}

// parallel exclusive scan: 1024 threads, 10 entries/thread, 2-level
__global__ __launch_bounds__(1024) void k_scan(const int* deg, int* rowptr){
  __shared__ int wsum[16];
  int t = threadIdx.x;
  int lane = t & 63, wv = t >> 6;
  const int CH = (N4 + 1023)/1024;      // 10
  int base = t*CH;
  int s = 0;
  #pragma unroll
  for (int i=0;i<CH;i++){ int idx=base+i; if (idx<N4) s += deg[idx]; }
  int inc = s;
  for (int d=1; d<64; d<<=1){
    int v = __shfl_up(inc, d, 64);
    if (lane >= d) inc += v;
  }
  if (lane == 63) wsum[wv] = inc;
  __syncthreads();
  int woff = 0;
  for (int i=0;i<wv;i++) woff += wsum[i];
  int run = woff + inc - s;
  #pragma unroll
  for (int i=0;i<CH;i++){
    int idx = base+i;
    if (idx < N4){ rowptr[idx] = run; run += deg[idx]; }
  }
  if (t == 1023) rowptr[N4] = woff + inc;
}

__global__ void k_fill(const int* tgt, const int* src, const int* rowptr, int* cursor,
                       int* elist, int2* epair){
  int e = blockIdx.x*256 + threadIdx.x;
  if (e < N_EDGES){
    int s = src[e];
    int b = (unsigned)s / BUKW;
    int slot_base = tgt[e]*NBUK + b;
    int pos = atomicAdd(&cursor[slot_base], 1);
    int slot = rowptr[slot_base] + pos;
    elist[slot] = e;
    int2 p; p.x = e; p.y = s;
    epair[slot] = p;
  }
}

// ---------------- edge features: 64 edges/block; GW=10 taps (bf16 We1); MFMA t1@we2t; OUT bf16 ----------------
__global__ __launch_bounds__(256) void k_efeat(const float* __restrict__ dist,
                                               const unsigned short* __restrict__ we1b,
                                               const unsigned short* __restrict__ we2t,
                                               unsigned short* __restrict__ efeat16){
  __shared__ float dsh[EB];
  __shared__ int j0s[EB];
  __shared__ int cns[EB];
  __shared__ __align__(16) unsigned short A16[EB*ASTR];   // 17408 B (t1 bf16)
  int t = threadIdx.x;
  int lane = t & 63;
  int e0 = blockIdx.x*EB;
  const float delta = 12.0f/599.0f;
  const float coeff = -0.5f/((2.0f*delta)*(2.0f*delta));
  if (t < EB){
    int e = e0 + t;
    float d = (e < N_EDGES) ? dist[e] : 0.f;
    int jc = (int)floorf(d/delta + 0.5f);
    int j0 = jc-GW; if (j0<0) j0=0;
    int j1 = jc+GW; if (j1>NB-1) j1=NB-1;
    dsh[t]=d; j0s[t]=j0; cns[t]=(e < N_EDGES)? (j1-j0+1) : 0;
  }
  __syncthreads();
  int hb = lane & 32;
  int myw = lane & 31;
  #pragma unroll
  for (int it=0; it<8; ++it){
    int task = t + (it<<8);
    int el = task >> 5, c4 = (task & 31)*4;
    float d = dsh[el]; int j0 = j0s[el]; int cn = cns[el];
    float gm = 0.f;
    if (myw < cn){
      float off = (float)(j0+myw)*delta;
      float dd = d-off;
      gm = __expf(coeff*dd*dd);
    }
    float a0=0.f,a1=0.f,a2=0.f,a3=0.f;
    for (int w=0; w<NTAP; ++w){
      float g = __shfl(gm, hb + w, 64);
      int row = j0+w; if (row > NB-1) row = NB-1;
      uint2 wv = *(const uint2*)&we1b[(size_t)row*C + c4];
      float2 w01 = bf2f2(wv.x);
      float2 w23 = bf2f2(wv.y);
      a0 += g*w01.x; a1 += g*w01.y; a2 += g*w23.x; a3 += g*w23.y;
    }
    *(unsigned*)&A16[el*ASTR + c4]     = pack2(silu(a0), silu(a1));
    *(unsigned*)&A16[el*ASTR + c4 + 2] = pack2(silu(a2), silu(a3));
  }
  __syncthreads();
  int w = t>>6;
  int lr = lane & 15, lg = lane >> 4;
  int colb = 32*w;
  f32x4 acc[4][2];
  #pragma unroll
  for (int rt=0;rt<4;rt++)
    #pragma unroll
    for (int ci=0;ci<2;ci++){ acc[rt][ci][0]=0.f; acc[rt][ci][1]=0.f; acc[rt][ci][2]=0.f; acc[rt][ci][3]=0.f; }
  #pragma unroll
  for (int ks=0; ks<4; ++ks){
    int k0 = ks*32 + lg*8;
    const unsigned short* Ab = &A16[lr*ASTR + k0];
    bf16x8 a0 = *(const bf16x8*)(Ab);
    bf16x8 a1 = *(const bf16x8*)(Ab + 16*ASTR);
    bf16x8 a2 = *(const bf16x8*)(Ab + 32*ASTR);
    bf16x8 a3 = *(const bf16x8*)(Ab + 48*ASTR);
    const unsigned short* Bb = &we2t[(colb + lr)*C + k0];
    bf16x8 b0 = *(const bf16x8*)(Bb);
    bf16x8 b1 = *(const bf16x8*)(Bb + 16*C);
    acc[0][0] = __builtin_amdgcn_mfma_f32_16x16x32_bf16(a0, b0, acc[0][0], 0, 0, 0);
    acc[1][0] = __builtin_amdgcn_mfma_f32_16x16x32_bf16(a1, b0, acc[1][0], 0, 0, 0);
    acc[2][0] = __builtin_amdgcn_mfma_f32_16x16x32_bf16(a2, b0, acc[2][0], 0, 0, 0);
    acc[3][0] = __builtin_amdgcn_mfma_f32_16x16x32_bf16(a3, b0, acc[3][0], 0, 0, 0);
    acc[0][1] = __builtin_amdgcn_mfma_f32_16x16x32_bf16(a0, b1, acc[0][1], 0, 0, 0);
    acc[1][1] = __builtin_amdgcn_mfma_f32_16x16x32_bf16(a1, b1, acc[1][1], 0, 0, 0);
    acc[2][1] = __builtin_amdgcn_mfma_f32_16x16x32_bf16(a2, b1, acc[2][1], 0, 0, 0);
    acc[3][1] = __builtin_amdgcn_mfma_f32_16x16x32_bf16(a3, b1, acc[3][1], 0, 0, 0);
  }
  #pragma unroll
  for (int rt=0;rt<4;rt++){
    #pragma unroll
    for (int ci=0;ci<2;ci++){
      int col = colb + 16*ci + lr;
      #pragma unroll
      for (int q=0;q<4;q++){
        int r = 16*rt + lg*4 + q;
        int e = e0 + r;
        if (e < N_EDGES)
          efeat16[(size_t)e*C + col] = bf16of(silu(acc[rt][ci][q]));
      }
    }
  }
}

// efsumT[c][n]  (reads bf16 efeat)
__global__ void k_efsum(const unsigned short* efeat16, const int* rowptr, const int* elist, float* efsumT){
  int n = blockIdx.x; int t = threadIdx.x; // 128 threads
  float acc = 0.f;
  int beg = rowptr[n*NBUK], end = rowptr[n*NBUK+NBUK];
  for (int i=beg;i<end;i++)
    acc += bf2f(efeat16[(size_t)elist[i]*C + t]);
  efsumT[(size_t)t*N_NODES + n] = acc;
}

// ---------------- deg-init ----------------
__global__ __launch_bounds__(256) void k_deginit(const float* __restrict__ efsumT, const float* __restrict__ Wdeg,
        const float* __restrict__ emb, const int* __restrict__ anum, float* __restrict__ x){
  __shared__ __align__(16) float efT[C][16];
  int t = threadIdx.x;
  int n0 = blockIdx.x*16;
  int grp = blockIdx.y;
  for (int q=t; q<16*C; q+=256){
    int cc=q>>4, nd=q&15;
    int n=n0+nd;
    efT[cc][nd] = (n<N_NODES)? efsumT[(size_t)cc*N_NODES + n] : 0.f;
  }
  __syncthreads();
  const float inv_avg = 1.0f/23.395238876342773f;
  int o = grp*512 + t*2;
  if (o < MC*C){
    float a0[16], a1[16];
    #pragma unroll
    for (int i=0;i<16;i++){ a0[i]=0.f; a1[i]=0.f; }
    for (int cc=0; cc<C; ++cc){
      float2 w = *(const float2*)&Wdeg[(size_t)cc*(MC*C)+o];
      float4 e0 = *(const float4*)&efT[cc][0];
      float4 e1 = *(const float4*)&efT[cc][4];
      float4 e2 = *(const float4*)&efT[cc][8];
      float4 e3 = *(const float4*)&efT[cc][12];
      a0[0]+=e0.x*w.x; a1[0]+=e0.x*w.y;
      a0[1]+=e0.y*w.x; a1[1]+=e0.y*w.y;
      a0[2]+=e0.z*w.x; a1[2]+=e0.z*w.y;
      a0[3]+=e0.w*w.x; a1[3]+=e0.w*w.y;
      a0[4]+=e1.x*w.x; a1[4]+=e1.x*w.y;
      a0[5]+=e1.y*w.x; a1[5]+=e1.y*w.y;
      a0[6]+=e1.z*w.x; a1[6]+=e1.z*w.y;
      a0[7]+=e1.w*w.x; a1[7]+=e1.w*w.y;
      a0[8]+=e2.x*w.x; a1[8]+=e2.x*w.y;
      a0[9]+=e2.y*w.x; a1[9]+=e2.y*w.y;
      a0[10]+=e2.z*w.x; a1[10]+=e2.z*w.y;
      a0[11]+=e2.w*w.x; a1[11]+=e2.w*w.y;
      a0[12]+=e3.x*w.x; a1[12]+=e3.x*w.y;
      a0[13]+=e3.y*w.x; a1[13]+=e3.y*w.y;
      a0[14]+=e3.z*w.x; a1[14]+=e3.z*w.y;
      a0[15]+=e3.w*w.x; a1[15]+=e3.w*w.y;
    }
    #pragma unroll
    for (int nd=0; nd<16; ++nd){
      int n = n0+nd;
      if (n < N_NODES){
        float v0 = a0[nd]*inv_avg, v1 = a1[nd]*inv_avg;
        if (o < C){ int an=anum[n]; v0 += emb[an*C+o]; v1 += emb[an*C+o+1]; }
        float2 st; st.x=v0; st.y=v1;
        *(float2*)&x[(size_t)n*MC*C + o] = st;
      }
    }
  }
}

// ---------------- FUSED nodeA (rmsnorm1+V, blocks 0..624) + QK proj (blocks 625..1256) ----------------
__global__ __launch_bounds__(256) void k_nAqk(const float* __restrict__ x, const float* __restrict__ scale0,
        const unsigned short* __restrict__ wvt, const unsigned short* __restrict__ wqt,
        const unsigned short* __restrict__ wkt,
        unsigned char* __restrict__ V, unsigned short* __restrict__ qb, unsigned short* __restrict__ kb){
  __shared__ __align__(16) char smem[26880];
  int t = threadIdx.x;
  int w = t>>6, lane = t&63;
  int lr = lane & 15, lg = lane >> 4;
  if (blockIdx.x < (unsigned)(N_NODES/4)){
    // ================= nodeA =================
    unsigned short* A16 = (unsigned short*)smem;    // 80*ASTR
    int n0 = blockIdx.x*4;
    {
      int n = n0 + w;
      float2 xv[MC];
      float pl[5]={0.f,0.f,0.f,0.f,0.f};
      #pragma unroll
      for (int m=0;m<MC;m++){
        float2 v = *(const float2*)&x[(size_t)n*MC*C + m*C + lane*2];
        xv[m]=v;
        pl[l_of_m(m)] += v.x*v.x + v.y*v.y;
      }
      #pragma unroll
      for (int l=0;l<5;l++){
        float r = pl[l];
        #pragma unroll
        for (int d=32; d>0; d>>=1) r += __shfl_xor(r, d, 64);
        pl[l]=r;
      }
      const float dens[5] = {128.f,384.f,640.f,896.f,1152.f};
      float inv[5];
      #pragma unroll
      for (int l=0;l<5;l++) inv[l] = 1.0f/sqrtf(pl[l]/dens[l] + 1e-8f);
      #pragma unroll
      for (int m=0;m<MC;m++){
        int l = l_of_m(m);
        float2 sc = *(const float2*)&scale0[l*C + lane*2];
        float a = xv[m].x*inv[l]*sc.x, b = xv[m].y*inv[l]*sc.y;
        *(unsigned*)&A16[(w*MC + m)*ASTR + lane*2] = pack2(a, b);
      }
    }
    for (int q=t; q<272; q+=256)
      ((unsigned*)A16)[(76*ASTR)/2 + q] = 0u;
    __syncthreads();
    int colb = 32*w;
    f32x4 acc[5][2];
    #pragma unroll
    for (int rt=0;rt<5;rt++)
      #pragma unroll
      for (int ci=0;ci<2;ci++){ acc[rt][ci][0]=0.f; acc[rt][ci][1]=0.f; acc[rt][ci][2]=0.f; acc[rt][ci][3]=0.f; }
    #pragma unroll
    for (int ks=0; ks<4; ++ks){
      int k0 = ks*32 + lg*8;
      const unsigned short* Ab = &A16[lr*ASTR + k0];
      bf16x8 a0 = *(const bf16x8*)(Ab);
      bf16x8 a1 = *(const bf16x8*)(Ab + 16*ASTR);
      bf16x8 a2 = *(const bf16x8*)(Ab + 32*ASTR);
      bf16x8 a3 = *(const bf16x8*)(Ab + 48*ASTR);
      bf16x8 a4 = *(const bf16x8*)(Ab + 64*ASTR);
      const unsigned short* Bb = &wvt[(colb + lr)*C + k0];
      bf16x8 b0 = *(const bf16x8*)(Bb);
      bf16x8 b1 = *(const bf16x8*)(Bb + 16*C);
      acc[0][0] = __builtin_amdgcn_mfma_f32_16x16x32_bf16(a0, b0, acc[0][0], 0, 0, 0);
      acc[1][0] = __builtin_amdgcn_mfma_f32_16x16x32_bf16(a1, b0, acc[1][0], 0, 0, 0);
      acc[2][0] = __builtin_amdgcn_mfma_f32_16x16x32_bf16(a2, b0, acc[2][0], 0, 0, 0);
      acc[3][0] = __builtin_amdgcn_mfma_f32_16x16x32_bf16(a3, b0, acc[3][0], 0, 0, 0);
      acc[4][0] = __builtin_amdgcn_mfma_f32_16x16x32_bf16(a4, b0, acc[4][0], 0, 0, 0);
      acc[0][1] = __builtin_amdgcn_mfma_f32_16x16x32_bf16(a0, b1, acc[0][1], 0, 0, 0);
      acc[1][1] = __builtin_amdgcn_mfma_f32_16x16x32_bf16(a1, b1, acc[1][1], 0, 0, 0);
      acc[2][1] = __builtin_amdgcn_mfma_f32_16x16x32_bf16(a2, b1, acc[2][1], 0, 0, 0);
      acc[3][1] = __builtin_amdgcn_mfma_f32_16x16x32_bf16(a3, b1, acc[3][1], 0, 0, 0);
      acc[4][1] = __builtin_amdgcn_mfma_f32_16x16x32_bf16(a4, b1, acc[4][1], 0, 0, 0);
    }
    __syncthreads();
    #pragma unroll
    for (int rt=0;rt<5;rt++){
      #pragma unroll
      for (int ci=0;ci<2;ci++){
        int col = colb + 16*ci + lr;
        #pragma unroll
        for (int q=0;q<4;q++){
          int r = 16*rt + lg*4 + q;
          A16[r*ASTR + col] = bf16of(acc[rt][ci][q]);
        }
      }
    }
    __syncthreads();
    for (int q=t; q<76*64; q+=256){
      int r = q>>6;
      int c2 = (q&63)*2;
      unsigned u = *(unsigned*)&A16[r*ASTR + c2];
      float2 f = bf2f2(u);
      *(unsigned short*)&V[((size_t)(n0*MC + r))*C + c2] = packfp8(f.x, f.y);
    }
  } else {
    // ================= QK =================
    int qq = blockIdx.x - N_NODES/4;
    int grp = qq / NQKB;
    int n0 = (qq - grp*NQKB)*32;
    float (*sn)[132] = (float(*)[132])smem;                     // 16896 B
    float (*ps)[8] = (float(*)[8])(smem + 16896);               // 1024 B
    float* invs = (float*)(smem + 16896 + 1024);                // 128 B
    unsigned short* A16 = (unsigned short*)(smem + 16896 + 1024 + 128);  // 8704 B
    const unsigned short* WTg = (grp < 4) ? wqt : wkt;
    int cb = (grp & 3)*128;
    unsigned short* outb = (grp < 4) ? qb : kb;
    {
      int nd = t>>3, seg = t&7;
      int n = n0+nd;
      float ss = 0.f;
      if (n < N_NODES){
        const float* xr = &x[(size_t)n*MC*C];
        #pragma unroll
        for (int i=0;i<16;i++){
          int c = seg*16+i;
          float v = xr[c];
          ss += v*v;
          sn[nd][c] = v*scale0[c];
        }
      } else {
        #pragma unroll
        for (int i=0;i<16;i++) sn[nd][seg*16+i] = 0.f;
      }
      ps[nd][seg] = ss;
    }
    __syncthreads();
    if (t < 32){
      float s = 0.f;
      #pragma unroll
      for (int i=0;i<8;i++) s += ps[t][i];
      invs[t] = 1.0f/sqrtf(s*(1.0f/128.f) + 1e-8f);
    }
    __syncthreads();
    for (int q=t; q<32*64; q+=256){
      int r = q>>6, c2 = (q&63)*2;
      float inv = invs[r];
      *(unsigned*)&A16[r*ASTR + c2] = pack2(sn[r][c2]*inv, sn[r][c2+1]*inv);
    }
    __syncthreads();
    int colb = 32*w;
    f32x4 acc[2][2];
    #pragma unroll
    for (int rt=0;rt<2;rt++)
      #pragma unroll
      for (int ci=0;ci<2;ci++){ acc[rt][ci][0]=0.f; acc[rt][ci][1]=0.f; acc[rt][ci][2]=0.f; acc[rt][ci][3]=0.f; }
    #pragma unroll
    for (int ks=0; ks<4; ++ks){
      int k0 = ks*32 + lg*8;
      const unsigned short* Ab = &A16[lr*ASTR + k0];
      bf16x8 a0 = *(const bf16x8*)(Ab);
      bf16x8 a1 = *(const bf16x8*)(Ab + 16*ASTR);
      const unsigned short* Bb = &WTg[(size_t)(cb + colb + lr)*C + k0];
      bf16x8 b0 = *(const bf16x8*)(Bb);
      bf16x8 b1 = *(const bf16x8*)(Bb + 16*C);
      acc[0][0] = __builtin_amdgcn_mfma_f32_16x16x32_bf16(a0, b0, acc[0][0], 0, 0, 0);
      acc[1][0] = __builtin_amdgcn_mfma_f32_16x16x32_bf16(a1, b0, acc[1][0], 0, 0, 0);
      acc[0][1] = __builtin_amdgcn_mfma_f32_16x16x32_bf16(a0, b1, acc[0][1], 0, 0, 0);
      acc[1][1] = __builtin_amdgcn_mfma_f32_16x16x32_bf16(a1, b1, acc[1][1], 0, 0, 0);
    }
    #pragma unroll
    for (int rt=0;rt<2;rt++){
      #pragma unroll
      for (int ci=0;ci<2;ci++){
        int col = colb + 16*ci + lr;
        #pragma unroll
        for (int q=0;q<4;q++){
          int r = 16*rt + lg*4 + q;
          int n = n0 + r;
          if (n < N_NODES)
            outb[(size_t)n*512 + cb + col] = bf16of(acc[rt][ci][q]);
        }
      }
    }
  }
}

// ---------------- FUSED attn (blocks 0..624) + rad (blocks 625..1406) ----------------
// rad: A-fragments DIRECT from global bf16 efeat16 (no LDS staging)
__global__ __launch_bounds__(256) void k_attnrad(const unsigned short* __restrict__ qb,
        const unsigned short* __restrict__ kb, const float* __restrict__ alpha,
        const int* __restrict__ rowptr, const int2* __restrict__ epair, float* __restrict__ attnb,
        const unsigned short* __restrict__ efeat16, const float* __restrict__ Wrad,
        float* __restrict__ radb){
  __shared__ __align__(16) char smem[13824];
  int t = threadIdx.x;
  int w = t>>6, lane = t&63;
  if (blockIdx.x < (unsigned)(N_NODES/4)){
    // ================= attn =================
    float (*lw)[MAXE][8] = (float(*)[MAXE][8])smem;     // 12288 B
    int (*eid)[MAXE] = (int(*)[MAXE])(smem + 12288);    // 1536 B
    int n = blockIdx.x*4 + w;
    float al[8];
    {
      float4 a0 = *(const float4*)&alpha[lane*8];
      float4 a1 = *(const float4*)&alpha[lane*8+4];
      al[0]=a0.x; al[1]=a0.y; al[2]=a0.z; al[3]=a0.w;
      al[4]=a1.x; al[5]=a1.y; al[6]=a1.z; al[7]=a1.w;
    }
    float qf[8];
    {
      int4 qv = *(const int4*)&qb[(size_t)n*512 + lane*8];
      unsigned qu[4] = {(unsigned)qv.x,(unsigned)qv.y,(unsigned)qv.z,(unsigned)qv.w};
      #pragma unroll
      for (int j=0;j<4;j++){
        float2 q2 = bf2f2(qu[j]);
        qf[2*j] = q2.x; qf[2*j+1] = q2.y;
      }
    }
    int beg = rowptr[n*NBUK], end = rowptr[n*NBUK+NBUK];
    int cnt = end - beg; if (cnt > MAXE) cnt = MAXE;
    int i = 0;
    for (; i+4 <= cnt; i += 4){
      int2 p0 = epair[beg+i];
      int2 p1 = epair[beg+i+1];
      int2 p2 = epair[beg+i+2];
      int2 p3 = epair[beg+i+3];
      int4 kv0 = *(const int4*)&kb[(size_t)p0.y*512 + lane*8];
      int4 kv1 = *(const int4*)&kb[(size_t)p1.y*512 + lane*8];
      int4 kv2 = *(const int4*)&kb[(size_t)p2.y*512 + lane*8];
      int4 kv3 = *(const int4*)&kb[(size_t)p3.y*512 + lane*8];
      unsigned ku0[4] = {(unsigned)kv0.x,(unsigned)kv0.y,(unsigned)kv0.z,(unsigned)kv0.w};
      unsigned ku1[4] = {(unsigned)kv1.x,(unsigned)kv1.y,(unsigned)kv1.z,(unsigned)kv1.w};
      unsigned ku2[4] = {(unsigned)kv2.x,(unsigned)kv2.y,(unsigned)kv2.z,(unsigned)kv2.w};
      unsigned ku3[4] = {(unsigned)kv3.x,(unsigned)kv3.y,(unsigned)kv3.z,(unsigned)kv3.w};
      float acc0 = 0.f, acc1 = 0.f, acc2 = 0.f, acc3 = 0.f;
      #pragma unroll
      for (int j=0;j<4;j++){
        float2 k0 = bf2f2(ku0[j]);
        float2 k1 = bf2f2(ku1[j]);
        float2 k2 = bf2f2(ku2[j]);
        float2 k3 = bf2f2(ku3[j]);
        acc0 += silu(qf[2*j]+k0.x)*al[2*j] + silu(qf[2*j+1]+k0.y)*al[2*j+1];
        acc1 += silu(qf[2*j]+k1.x)*al[2*j] + silu(qf[2*j+1]+k1.y)*al[2*j+1];
        acc2 += silu(qf[2*j]+k2.x)*al[2*j] + silu(qf[2*j+1]+k2.y)*al[2*j+1];
        acc3 += silu(qf[2*j]+k3.x)*al[2*j] + silu(qf[2*j+1]+k3.y)*al[2*j+1];
      }
      #pragma unroll
      for (int d=1; d<8; d<<=1){
        acc0 += __shfl_down(acc0, d, 64);
        acc1 += __shfl_down(acc1, d, 64);
        acc2 += __shfl_down(acc2, d, 64);
        acc3 += __shfl_down(acc3, d, 64);
      }
      if ((lane&7)==0){
        lw[w][i][lane>>3]   = acc0 * 0.125f;
        lw[w][i+1][lane>>3] = acc1 * 0.125f;
        lw[w][i+2][lane>>3] = acc2 * 0.125f;
        lw[w][i+3][lane>>3] = acc3 * 0.125f;
      }
      if (lane==0){
        eid[w][i] = p0.x; eid[w][i+1] = p1.x;
        eid[w][i+2] = p2.x; eid[w][i+3] = p3.x;
      }
    }
    for (; i < cnt; ++i){
      int2 p0 = epair[beg+i];
      int4 kv0 = *(const int4*)&kb[(size_t)p0.y*512 + lane*8];
      unsigned ku0[4] = {(unsigned)kv0.x,(unsigned)kv0.y,(unsigned)kv0.z,(unsigned)kv0.w};
      float acc0 = 0.f;
      #pragma unroll
      for (int j=0;j<4;j++){
        float2 k0 = bf2f2(ku0[j]);
        acc0 += silu(qf[2*j]+k0.x)*al[2*j] + silu(qf[2*j+1]+k0.y)*al[2*j+1];
      }
      #pragma unroll
      for (int d=1; d<8; d<<=1) acc0 += __shfl_down(acc0, d, 64);
      if ((lane&7)==0) lw[w][i][lane>>3] = acc0 * 0.125f;
      if (lane==0) eid[w][i] = p0.x;
    }
    __syncthreads();
    int h = lane & 7, ec = lane >> 3;
    float mx = -1e30f;
    for (int q=ec; q<cnt; q+=8) mx = fmaxf(mx, lw[w][q][h]);
    #pragma unroll
    for (int dd=8; dd<64; dd<<=1) mx = fmaxf(mx, __shfl_xor(mx, dd, 64));
    float sum = 0.f;
    for (int q=ec; q<cnt; q+=8) sum += __expf(lw[w][q][h] - mx);
    #pragma unroll
    for (int dd=8; dd<64; dd<<=1) sum += __shfl_xor(sum, dd, 64);
    float inv = 1.0f/(sum + 1e-9f);
    for (int q=ec; q<cnt; q+=8)
      attnb[eid[w][q]*8 + h] = __expf(lw[w][q][h] - mx) * inv;
  } else {
    // ================= rad (A direct from global bf16) =================
    unsigned short* WT = (unsigned short*)smem;              // 32*ASTR*2 = 8704
    int e0 = (blockIdx.x - N_NODES/4)*EB;
    for (int q=t; q<32*64; q+=256){
      int m = q>>6, c2 = (q&63)*2;
      float w0 = (m < MC) ? Wrad[(size_t)c2*MC + m] : 0.f;
      float w1 = (m < MC) ? Wrad[(size_t)(c2+1)*MC + m] : 0.f;
      *(unsigned*)&WT[m*ASTR + c2] = pack2(w0, w1);
    }
    __syncthreads();
    int lr = lane & 15, lg = lane >> 4;
    f32x4 acc[2];
    acc[0][0]=0.f; acc[0][1]=0.f; acc[0][2]=0.f; acc[0][3]=0.f;
    acc[1][0]=0.f; acc[1][1]=0.f; acc[1][2]=0.f; acc[1][3]=0.f;
    const unsigned short* Ag = &efeat16[(size_t)(e0 + 16*w + lr)*C];
    #pragma unroll
    for (int ks=0; ks<4; ++ks){
      int k0 = ks*32 + lg*8;
      bf16x8 a  = *(const bf16x8*)(Ag + k0);
      bf16x8 b0 = *(const bf16x8*)&WT[lr*ASTR + k0];
      bf16x8 b1 = *(const bf16x8*)&WT[(16+lr)*ASTR + k0];
      acc[0] = __builtin_amdgcn_mfma_f32_16x16x32_bf16(a, b0, acc[0], 0, 0, 0);
      acc[1] = __builtin_amdgcn_mfma_f32_16x16x32_bf16(a, b1, acc[1], 0, 0, 0);
    }
    #pragma unroll
    for (int ci=0;ci<2;ci++){
      int m = 16*ci + lr;
      #pragma unroll
      for (int q=0;q<4;q++){
        int r = 16*w + lg*4 + q;
        int e = e0 + r;
        if (m < MC && e < N_EDGES)
          radb[(size_t)e*RSTR + m] = silu(acc[ci][q]);
      }
    }
  }
}

// msum[n,m,d] = sum_e attn*rad*V (V fp8 e4m3); MFMA Wo epilogue with B direct from wot
#define CONS1(vv, ar)  { \
    floatx2 g0 = __builtin_amdgcn_cvt_pk_f32_fp8((vv).x, false); \
    floatx2 g1 = __builtin_amdgcn_cvt_pk_f32_fp8((vv).x, true);  \
    floatx2 g2 = __builtin_amdgcn_cvt_pk_f32_fp8((vv).y, false); \
    floatx2 g3 = __builtin_amdgcn_cvt_pk_f32_fp8((vv).y, true);  \
    acc1[0] += (ar)*g0[0]; acc1[1] += (ar)*g0[1]; \
    acc1[2] += (ar)*g1[0]; acc1[3] += (ar)*g1[1]; \
    acc1[4] += (ar)*g2[0]; acc1[5] += (ar)*g2[1]; \
    acc1[6] += (ar)*g3[0]; acc1[7] += (ar)*g3[1]; }
#define CONS2(vv, ar)  { \
    floatx2 g0 = __builtin_amdgcn_cvt_pk_f32_fp8((vv).x, false); \
    floatx2 g1 = __builtin_amdgcn_cvt_pk_f32_fp8((vv).x, true);  \
    floatx2 g2 = __builtin_amdgcn_cvt_pk_f32_fp8((vv).y, false); \
    floatx2 g3 = __builtin_amdgcn_cvt_pk_f32_fp8((vv).y, true);  \
    acc2[0] += (ar)*g0[0]; acc2[1] += (ar)*g0[1]; \
    acc2[2] += (ar)*g1[0]; acc2[3] += (ar)*g1[1]; \
    acc2[4] += (ar)*g2[0]; acc2[5] += (ar)*g2[1]; \
    acc2[6] += (ar)*g3[0]; acc2[7] += (ar)*g3[1]; }
__global__ __launch_bounds__(256, 4) void k_e1(const unsigned char* __restrict__ V, const float* __restrict__ radb,
        const float* __restrict__ attnb, const unsigned short* __restrict__ wot,
        const int* __restrict__ rowptr, const int2* __restrict__ epair,
        float* __restrict__ x){
  __shared__ __align__(16) float msum[32*MSTR];           // 16896 B (rows 19..31 zero)
  int n = blockIdx.x;
  int t = threadIdx.x;
  int w = t>>6, lane = t&63;
  for (int q=t; q<13*MSTR; q+=256) msum[19*MSTR + q] = 0.f;
  int chunk = lane & 15;
  int g = lane >> 4;
  int m1 = w*5 + g;
  int c1 = chunk*8;
  int h1 = chunk>>1;
  int m2 = w*5 + 4;
  bool has2 = (w < 3) && (lane < 16);
  int voff1 = m1*C + c1;
  int voff2 = m2*C + lane*8;
  int h2 = lane>>1;
  float acc1[8], acc2[8];
  #pragma unroll
  for (int j=0;j<8;j++){ acc1[j]=0.f; acc2[j]=0.f; }
  int beg = rowptr[n*NBUK], end = rowptr[n*NBUK+NBUK];
  int idx = beg;
  // ---- 8-edge unrolled gather (double the in-flight loads vs 4) ----
  for (; idx+8 <= end; idx += 8){
    int2 pp[8];
    #pragma unroll
    for (int u=0;u<8;u++) pp[u] = epair[idx+u];
    int2 va[8];
    float ra[8];
    #pragma unroll
    for (int u=0;u<8;u++){
      const unsigned char* vb = V + (size_t)pp[u].y*(MC*C);
      va[u] = *(const int2*)(vb + voff1);
    }
    #pragma unroll
    for (int u=0;u<8;u++)
      ra[u] = attnb[pp[u].x*8 + h1] * radb[(size_t)pp[u].x*RSTR + m1];
    int2 wa[8];
    float qa[8];
    if (has2){
      #pragma unroll
      for (int u=0;u<8;u++){
        const unsigned char* vb = V + (size_t)pp[u].y*(MC*C);
        wa[u] = *(const int2*)(vb + voff2);
        qa[u] = attnb[pp[u].x*8 + h2] * radb[(size_t)pp[u].x*RSTR + m2];
      }
    }
    #pragma unroll
    for (int u=0;u<8;u++){ CONS1(va[u], ra[u]); }
    if (has2){
      #pragma unroll
      for (int u=0;u<8;u++){ CONS2(wa[u], qa[u]); }
    }
  }
  for (; idx+4 <= end; idx += 4){
    int2 p0 = epair[idx];
    int2 p1 = epair[idx+1];
    int2 p2 = epair[idx+2];
    int2 p3 = epair[idx+3];
    const unsigned char* vb0 = V + (size_t)p0.y*(MC*C);
    const unsigned char* vb1 = V + (size_t)p1.y*(MC*C);
    const unsigned char* vb2 = V + (size_t)p2.y*(MC*C);
    const unsigned char* vb3 = V + (size_t)p3.y*(MC*C);
    int2 va0 = *(const int2*)(vb0 + voff1);
    int2 va1 = *(const int2*)(vb1 + voff1);
    int2 va2 = *(const int2*)(vb2 + voff1);
    int2 va3 = *(const int2*)(vb3 + voff1);
    float ra0 = attnb[p0.x*8 + h1] * radb[(size_t)p0.x*RSTR + m1];
    float ra1 = attnb[p1.x*8 + h1] * radb[(size_t)p1.x*RSTR + m1];
    float ra2 = attnb[p2.x*8 + h1] * radb[(size_t)p2.x*RSTR + m1];
    float ra3 = attnb[p3.x*8 + h1] * radb[(size_t)p3.x*RSTR + m1];
    int2 wa0, wa1, wa2, wa3;
    float qa0=0.f, qa1=0.f, qa2=0.f, qa3=0.f;
    if (has2){
      wa0 = *(const int2*)(vb0 + voff2);
      wa1 = *(const int2*)(vb1 + voff2);
      wa2 = *(const int2*)(vb2 + voff2);
      wa3 = *(const int2*)(vb3 + voff2);
      qa0 = attnb[p0.x*8 + h2] * radb[(size_t)p0.x*RSTR + m2];
      qa1 = attnb[p1.x*8 + h2] * radb[(size_t)p1.x*RSTR + m2];
      qa2 = attnb[p2.x*8 + h2] * radb[(size_t)p2.x*RSTR + m2];
      qa3 = attnb[p3.x*8 + h2] * radb[(size_t)p3.x*RSTR + m2];
    }
    CONS1(va0, ra0);
    CONS1(va1, ra1);
    CONS1(va2, ra2);
    CONS1(va3, ra3);
    if (has2){
      CONS2(wa0, qa0);
      CONS2(wa1, qa1);
      CONS2(wa2, qa2);
      CONS2(wa3, qa3);
    }
  }
  for (; idx < end; ++idx){
    int2 p0 = epair[idx];
    const unsigned char* vb = V + (size_t)p0.y*(MC*C);
    int2 va = *(const int2*)(vb + voff1);
    float ra = attnb[p0.x*8 + h1] * radb[(size_t)p0.x*RSTR + m1];
    int2 wa; float qa = 0.f;
    if (has2){
      wa = *(const int2*)(vb + voff2);
      qa = attnb[p0.x*8 + h2] * radb[(size_t)p0.x*RSTR + m2];
    }
    CONS1(va, ra);
    if (has2){ CONS2(wa, qa); }
  }
  {
    float4 st0; st0.x=acc1[0]; st0.y=acc1[1]; st0.z=acc1[2]; st0.w=acc1[3];
    float4 st1; st1.x=acc1[4]; st1.y=acc1[5]; st1.z=acc1[6]; st1.w=acc1[7];
    *(float4*)&msum[m1*MSTR + c1]     = st0;
    *(float4*)&msum[m1*MSTR + c1 + 4] = st1;
    if (has2){
      float4 s2a; s2a.x=acc2[0]; s2a.y=acc2[1]; s2a.z=acc2[2]; s2a.w=acc2[3];
      float4 s2b; s2b.x=acc2[4]; s2b.y=acc2[5]; s2b.z=acc2[6]; s2b.w=acc2[7];
      *(float4*)&msum[m2*MSTR + lane*8]     = s2a;
      *(float4*)&msum[m2*MSTR + lane*8 + 4] = s2b;
    }
  }
  __syncthreads();
  int lr = lane & 15, lg = lane >> 4;
  int colb = 32*w;
  f32x4 eacc[2][2];
  #pragma unroll
  for (int rt=0;rt<2;rt++)
    #pragma unroll
    for (int ci=0;ci<2;ci++){ eacc[rt][ci][0]=0.f; eacc[rt][ci][1]=0.f; eacc[rt][ci][2]=0.f; eacc[rt][ci][3]=0.f; }
  #pragma unroll
  for (int ks=0; ks<4; ++ks){
    int k0 = ks*32 + lg*8;
    float4 a0lo = *(const float4*)&msum[lr*MSTR + k0];
    float4 a0hi = *(const float4*)&msum[lr*MSTR + k0 + 4];
    float4 a1lo = *(const float4*)&msum[(lr+16)*MSTR + k0];
    float4 a1hi = *(const float4*)&msum[(lr+16)*MSTR + k0 + 4];
    bf16x8 a0 = packbf8(a0lo, a0hi);
    bf16x8 a1 = packbf8(a1lo, a1hi);
    const unsigned short* Bb = &wot[(colb + lr)*C + k0];
    bf16x8 b0 = *(const bf16x8*)(Bb);
    bf16x8 b1 = *(const bf16x8*)(Bb + 16*C);
    eacc[0][0] = __builtin_amdgcn_mfma_f32_16x16x32_bf16(a0, b0, eacc[0][0], 0, 0, 0);
    eacc[1][0] = __builtin_amdgcn_mfma_f32_16x16x32_bf16(a1, b0, eacc[1][0], 0, 0, 0);
    eacc[0][1] = __builtin_amdgcn_mfma_f32_16x16x32_bf16(a0, b1, eacc[0][1], 0, 0, 0);
    eacc[1][1] = __builtin_amdgcn_mfma_f32_16x16x32_bf16(a1, b1, eacc[1][1], 0, 0, 0);
  }
  #pragma unroll
  for (int rt=0;rt<2;rt++){
    #pragma unroll
    for (int ci=0;ci<2;ci++){
      int col = colb + 16*ci + lr;
      #pragma unroll
      for (int q=0;q<4;q++){
        int r = 16*rt + lg*4 + q;
        if (r < MC){
          size_t off = (size_t)n*MC*C + r*C + col;
          x[off] += eacc[rt][ci][q];
        }
      }
    }
  }
}

// ---------------- rmsnorm2 + gated FFN via MFMA, 4 nodes/block; B direct from w1t/w2t ----------------
__global__ __launch_bounds__(256) void k_nodeB(float* __restrict__ x, const float* __restrict__ scale,
        const unsigned short* __restrict__ w1t, const unsigned short* __restrict__ w2t){
  __shared__ __align__(16) unsigned short A16[80*ASTR];   // 21760 B (A, then hb)
  __shared__ float gate[4*C];                             // 2048 B
  int t = threadIdx.x;
  int n0 = blockIdx.x*4;
  int w = t>>6, lane = t&63;
  int lr = lane & 15, lg = lane >> 4;
  {
    int n = n0 + w;
    float2 xv[MC];
    float pl[5]={0.f,0.f,0.f,0.f,0.f};
    #pragma unroll
    for (int m=0;m<MC;m++){
      float2 v = *(const float2*)&x[(size_t)n*MC*C + m*C + lane*2];
      xv[m]=v;
      pl[l_of_m(m)] += v.x*v.x + v.y*v.y;
    }
    #pragma unroll
    for (int l=0;l<5;l++){
      float r = pl[l];
      #pragma unroll
      for (int d=32; d>0; d>>=1) r += __shfl_xor(r, d, 64);
      pl[l]=r;
    }
    const float dens[5] = {128.f,384.f,640.f,896.f,1152.f};
    float inv[5];
    #pragma unroll
    for (int l=0;l<5;l++) inv[l] = 1.0f/sqrtf(pl[l]/dens[l] + 1e-8f);
    #pragma unroll
    for (int m=0;m<MC;m++){
      int l = l_of_m(m);
      float2 sc = *(const float2*)&scale[l*C + lane*2];
      float a = xv[m].x*inv[l]*sc.x, b = xv[m].y*inv[l]*sc.y;
      *(unsigned*)&A16[(w*MC + m)*ASTR + lane*2] = pack2(a, b);
    }
  }
  for (int q=t; q<272; q+=256)
    ((unsigned*)A16)[(76*ASTR)/2 + q] = 0u;
  __syncthreads();
  int colb = 32*w;
  f32x4 acc[5][2];
  #pragma unroll
  for (int rt=0;rt<5;rt++)
    #pragma unroll
    for (int ci=0;ci<2;ci++){ acc[rt][ci][0]=0.f; acc[rt][ci][1]=0.f; acc[rt][ci][2]=0.f; acc[rt][ci][3]=0.f; }
  #pragma unroll
  for (int ks=0; ks<4; ++ks){
    int k0 = ks*32 + lg*8;
    const unsigned short* Ab = &A16[lr*ASTR + k0];
    bf16x8 a0 = *(const bf16x8*)(Ab);
    bf16x8 a1 = *(const bf16x8*)(Ab + 16*ASTR);
    bf16x8 a2 = *(const bf16x8*)(Ab + 32*ASTR);
    bf16x8 a3 = *(const bf16x8*)(Ab + 48*ASTR);
    bf16x8 a4 = *(const bf16x8*)(Ab + 64*ASTR);
    const unsigned short* Bb = &w1t[(colb + lr)*C + k0];
    bf16x8 b0 = *(const bf16x8*)(Bb);
    bf16x8 b1 = *(const bf16x8*)(Bb + 16*C);
    acc[0][0] = __builtin_amdgcn_mfma_f32_16x16x32_bf16(a0, b0, acc[0][0], 0, 0, 0);
    acc[1][0] = __builtin_amdgcn_mfma_f32_16x16x32_bf16(a1, b0, acc[1][0], 0, 0, 0);
    acc[2][0] = __builtin_amdgcn_mfma_f32_16x16x32_bf16(a2, b0, acc[2][0], 0, 0, 0);
    acc[3][0] = __builtin_amdgcn_mfma_f32_16x16x32_bf16(a3, b0, acc[3][0], 0, 0, 0);
    acc[4][0] = __builtin_amdgcn_mfma_f32_16x16x32_bf16(a4, b0, acc[4][0], 0, 0, 0);
    acc[0][1] = __builtin_amdgcn_mfma_f32_16x16x32_bf16(a0, b1, acc[0][1], 0, 0, 0);
    acc[1][1] = __builtin_amdgcn_mfma_f32_16x16x32_bf16(a1, b1, acc[1][1], 0, 0, 0);
    acc[2][1] = __builtin_amdgcn_mfma_f32_16x16x32_bf16(a2, b1, acc[2][1], 0, 0, 0);
    acc[3][1] = __builtin_amdgcn_mfma_f32_16x16x32_bf16(a3, b1, acc[3][1], 0, 0, 0);
    acc[4][1] = __builtin_amdgcn_mfma_f32_16x16x32_bf16(a4, b1, acc[4][1], 0, 0, 0);
  }
  __syncthreads();
  #pragma unroll
  for (int rt=0;rt<5;rt++){
    #pragma unroll
    for (int ci=0;ci<2;ci++){
      int col = colb + 16*ci + lr;
      #pragma unroll
      for (int q=0;q<4;q++){
        int r = 16*rt + lg*4 + q;
        A16[r*ASTR + col] = bf16of(acc[rt][ci][q]);
      }
    }
  }
  __syncthreads();
  #pragma unroll
  for (int i=0;i<2;++i){
    int id = t + (i<<8);
    int j = id>>7, c = id&127;
    float v = __uint_as_float(((unsigned)A16[(j*MC)*ASTR + c]) << 16);
    gate[j*C + c] = silu(v);
  }
  __syncthreads();
  for (int q=t; q<76*64; q+=256){
    int r = q>>6;
    int c2 = (q&63)*2;
    int j = r/MC;
    unsigned u = *(unsigned*)&A16[r*ASTR + c2];
    float2 f = bf2f2(u);
    f.x *= gate[j*C + c2];
    f.y *= gate[j*C + c2 + 1];
    *(unsigned*)&A16[r*ASTR + c2] = pack2(f.x, f.y);
  }
  __syncthreads();
  #pragma unroll
  for (int rt=0;rt<5;rt++)
    #pragma unroll
    for (int ci=0;ci<2;ci++){ acc[rt][ci][0]=0.f; acc[rt][ci][1]=0.f; acc[rt][ci][2]=0.f; acc[rt][ci][3]=0.f; }
  #pragma unroll
  for (int ks=0; ks<4; ++ks){
    int k0 = ks*32 + lg*8;
    const unsigned short* Ab = &A16[lr*ASTR + k0];
    bf16x8 a0 = *(const bf16x8*)(Ab);
    bf16x8 a1 = *(const bf16x8*)(Ab + 16*ASTR);
    bf16x8 a2 = *(const bf16x8*)(Ab + 32*ASTR);
    bf16x8 a3 = *(const bf16x8*)(Ab + 48*ASTR);
    bf16x8 a4 = *(const bf16x8*)(Ab + 64*ASTR);
    const unsigned short* Bb = &w2t[(colb + lr)*C + k0];
    bf16x8 b0 = *(const bf16x8*)(Bb);
    bf16x8 b1 = *(const bf16x8*)(Bb + 16*C);
    acc[0][0] = __builtin_amdgcn_mfma_f32_16x16x32_bf16(a0, b0, acc[0][0], 0, 0, 0);
    acc[1][0] = __builtin_amdgcn_mfma_f32_16x16x32_bf16(a1, b0, acc[1][0], 0, 0, 0);
    acc[2][0] = __builtin_amdgcn_mfma_f32_16x16x32_bf16(a2, b0, acc[2][0], 0, 0, 0);
    acc[3][0] = __builtin_amdgcn_mfma_f32_16x16x32_bf16(a3, b0, acc[3][0], 0, 0, 0);
    acc[4][0] = __builtin_amdgcn_mfma_f32_16x16x32_bf16(a4, b0, acc[4][0], 0, 0, 0);
    acc[0][1] = __builtin_amdgcn_mfma_f32_16x16x32_bf16(a0, b1, acc[0][1], 0, 0, 0);
    acc[1][1] = __builtin_amdgcn_mfma_f32_16x16x32_bf16(a1, b1, acc[1][1], 0, 0, 0);
    acc[2][1] = __builtin_amdgcn_mfma_f32_16x16x32_bf16(a2, b1, acc[2][1], 0, 0, 0);
    acc[3][1] = __builtin_amdgcn_mfma_f32_16x16x32_bf16(a3, b1, acc[3][1], 0, 0, 0);
    acc[4][1] = __builtin_amdgcn_mfma_f32_16x16x32_bf16(a4, b1, acc[4][1], 0, 0, 0);
  }
  #pragma unroll
  for (int rt=0;rt<5;rt++){
    #pragma unroll
    for (int ci=0;ci<2;ci++){
      int col = colb + 16*ci + lr;
      #pragma unroll
      for (int q=0;q<4;q++){
        int r = 16*rt + lg*4 + q;
        if (r < 4*MC){
          size_t off = ((size_t)(n0*MC + r))*C + col;
          x[off] += acc[rt][ci][q];
        }
      }
    }
  }
}

// ---------------- final head ----------------
__global__ __launch_bounds__(128) void k_final(const float* x, const float* nsf, const float* Wef1,
        const float* Wef2, const int* batch, float* out){
  __shared__ float sl[C];
  __shared__ float red[2];
  __shared__ float red2[2];
  int n = blockIdx.x; int t = threadIdx.x;
  float v = x[(size_t)n*MC*C + t];
  float sq = v*v;
  for (int d=32; d>0; d>>=1) sq += __shfl_down(sq, d, 64);
  if ((t&63)==0) red[t>>6] = sq;
  __syncthreads();
  float ms = (red[0]+red[1]) * (1.0f/128.f);
  float inv = 1.0f/sqrtf(ms + 1e-8f);
  sl[t] = v*inv*nsf[t];
  __syncthreads();
  float acc = 0.f;
  for (int cc=0; cc<C; ++cc) acc += sl[cc]*Wef1[cc*C + t];
  float val = acc*silu(acc)*Wef2[t];
  for (int d=32; d>0; d>>=1) val += __shfl_down(val, d, 64);
  if ((t&63)==0) red2[t>>6] = val;
  __syncthreads();
  if (t==0){
    float ne = red2[0]+red2[1];
    atomicAdd(&out[batch[n]], ne * (1.0f/77.81317f));
  }
}

extern "C" void kernel_launch(void* const* d_in, const int* in_sizes, int n_in,
                              void* d_out, int out_size, void* d_ws, size_t ws_size,
                              hipStream_t stream){
  (void)in_sizes; (void)n_in; (void)ws_size;
  const int*   anum  = (const int*)d_in[0];
  const int*   eidx  = (const int*)d_in[1];
  const float* dist  = (const float*)d_in[2];
  const int*   batch = (const int*)d_in[3];
  const float* emb   = (const float*)d_in[4];
  const float* We1   = (const float*)d_in[5];
  const float* We2   = (const float*)d_in[6];
  const float* Wdeg  = (const float*)d_in[7];
  const float* ns1   = (const float*)d_in[8];
  const float* ns2   = (const float*)d_in[9];
  const float* Wq    = (const float*)d_in[10];
  const float* Wk    = (const float*)d_in[11];
  const float* alpha = (const float*)d_in[12];
  const float* Wv    = (const float*)d_in[13];
  const float* Wrad  = (const float*)d_in[14];
  const float* Wo    = (const float*)d_in[15];
  const float* W1    = (const float*)d_in[16];
  const float* W2    = (const float*)d_in[17];
  const float* nsf   = (const float*)d_in[18];
  const float* Wef1  = (const float*)d_in[19];
  const float* Wef2  = (const float*)d_in[20];
  float* out = (float*)d_out;

  const int* srcarr = eidx;
  const int* tgtarr = eidx + N_EDGES;

  char* wsb = (char*)d_ws;
  unsigned short* efeat16 = (unsigned short*)wsb; wsb += (size_t)(NRADB*EB)*C*2;  // bf16, padded
  float* efsumT= (float*)wsb;  wsb += (size_t)N_NODES*C*4;
  float* x     = (float*)wsb;  wsb += (size_t)N_NODES*MC*C*4;
  unsigned char* Vb = (unsigned char*)wsb; wsb += (size_t)N_NODES*MC*C;    // fp8
  unsigned short* qb = (unsigned short*)wsb; wsb += (size_t)N_NODES*512*2;
  unsigned short* kb = (unsigned short*)wsb; wsb += (size_t)N_NODES*512*2;
  float* attnb = (float*)wsb;  wsb += (size_t)N_EDGES*8*4;
  float* radb  = (float*)wsb;  wsb += (size_t)N_EDGES*RSTR*4;
  int* deg     = (int*)wsb;    wsb += (size_t)N4*4;
  int* rowptr  = (int*)wsb;    wsb += (size_t)(N4+1)*4;
  int* cursor  = (int*)wsb;    wsb += (size_t)N4*4;
  int* elist   = (int*)wsb;    wsb += (size_t)N_EDGES*4;
  int2* epair  = (int2*)wsb;   wsb += (size_t)N_EDGES*8;
  unsigned short* we2t = (unsigned short*)wsb; wsb += (size_t)16384*2;
  unsigned short* wvt  = (unsigned short*)wsb; wsb += (size_t)4*16384*2;
  unsigned short* wot  = (unsigned short*)wsb; wsb += (size_t)4*16384*2;
  unsigned short* w1t  = (unsigned short*)wsb; wsb += (size_t)4*16384*2;
  unsigned short* w2t  = (unsigned short*)wsb; wsb += (size_t)4*16384*2;
  unsigned short* wqt  = (unsigned short*)wsb; wsb += (size_t)4*65536*2;
  unsigned short* wkt  = (unsigned short*)wsb; wsb += (size_t)4*65536*2;
  unsigned short* we1b = (unsigned short*)wsb; wsb += (size_t)NB*C*2;

  (void)hipMemsetAsync(deg, 0, N4*4, stream);
  (void)hipMemsetAsync(cursor, 0, N4*4, stream);
  (void)hipMemsetAsync(d_out, 0, (size_t)out_size*sizeof(float), stream);

  k_packall<<<1718, 256, 0, stream>>>(We2, Wv, Wo, W1, W2, Wq, Wk, We1,
                                      we2t, wvt, wot, w1t, w2t, wqt, wkt, we1b);
  k_count<<<(N_EDGES+255)/256, 256, 0, stream>>>(tgtarr, srcarr, deg);
  k_scan<<<1, 1024, 0, stream>>>(deg, rowptr);
  k_fill<<<(N_EDGES+255)/256, 256, 0, stream>>>(tgtarr, srcarr, rowptr, cursor, elist, epair);
  k_efeat<<<NRADB, 256, 0, stream>>>(dist, we1b, we2t, efeat16);
  k_efsum<<<N_NODES, 128, 0, stream>>>(efeat16, rowptr, elist, efsumT);
  k_deginit<<<dim3((N_NODES+15)/16, 5), 256, 0, stream>>>(efsumT, Wdeg, emb, anum, x);

  for (int i=0;i<NL;i++){
    k_nAqk<<<N_NODES/4 + NQKB*8, 256, 0, stream>>>(x, ns1 + i*5*C,
                                                   wvt + (size_t)i*16384,
                                                   wqt + (size_t)i*65536, wkt + (size_t)i*65536,
                                                   Vb, qb, kb);
    k_attnrad<<<N_NODES/4 + NRADB, 256, 0, stream>>>(qb, kb, alpha + i*512, rowptr, epair, attnb,
                                                     efeat16, Wrad + i*C*MC, radb);
    k_e1<<<N_NODES, 256, 0, stream>>>(Vb, radb, attnb, wot + (size_t)i*16384,
                                      rowptr, epair, x);
    k_nodeB<<<N_NODES/4, 256, 0, stream>>>(x, ns2 + i*5*C, w1t + (size_t)i*16384, w2t + (size_t)i*16384);
  }
  k_final<<<N_NODES, 128, 0, stream>>>(x, nsf, Wef1, Wef2, batch, out);
}

// Round 20
// 635.284 us; speedup vs baseline: 1.2776x; 1.2776x over previous
//
#include <hip/hip_runtime.h>
#include <hip/hip_bf16.h>

#define N_NODES 2500
#define N_EDGES 50000
#define C 128
#define MC 19
#define RSTR 20
#define NL 4
#define NB 600
#define GW 10
#define NTAP (2*GW+1)
#define NBUK 4
#define BUKW 625
#define N4 (N_NODES*NBUK)
#define ASTR 136   // bf16 LDS row stride (128 + 8 pad)
#define MSTR 132   // f32 msum row stride (128 + 4 pad)
#define MAXE 96    // per-node edge cap in k_attn
#define EB 64      // edges per k_efeat/k_rad block
#define NQKB ((N_NODES+31)/32)   // 79
#define NRADB ((N_EDGES+EB-1)/EB) // 782

typedef float floatx2 __attribute__((ext_vector_type(2)));
typedef short bf16x8 __attribute__((ext_vector_type(8)));
typedef float f32x4 __attribute__((ext_vector_type(4)));

__device__ __forceinline__ float silu(float v){ return v / (1.f + __expf(-v)); }
__device__ __forceinline__ int l_of_m(int m){
  return (m==0)?0 : (m<4)?1 : (m<9)?2 : (m<14)?3 : 4;
}
__device__ __forceinline__ unsigned pack2(float a, float b){
  __hip_bfloat162 h2;
  h2.x = __float2bfloat16(a);
  h2.y = __float2bfloat16(b);
  return *(unsigned*)&h2;
}
__device__ __forceinline__ unsigned short bf16of(float v){
  __hip_bfloat16 h = __float2bfloat16(v);
  return *(unsigned short*)&h;
}
__device__ __forceinline__ float bf2f(unsigned short u){
  return __uint_as_float(((unsigned)u) << 16);
}
__device__ __forceinline__ float2 bf2f2(unsigned u){
  float2 r;
  r.x = __uint_as_float(u << 16);
  r.y = __uint_as_float(u & 0xffff0000u);
  return r;
}
__device__ __forceinline__ bf16x8 packbf8(float4 a, float4 b){
  union { unsigned u[4]; bf16x8 v; } r;
  r.u[0] = pack2(a.x, a.y); r.u[1] = pack2(a.z, a.w);
  r.u[2] = pack2(b.x, b.y); r.u[3] = pack2(b.z, b.w);
  return r.v;
}
// pack 2 f32 -> 2 fp8 e4m3 (low 16 bits); values pre-clamped to +-448
__device__ __forceinline__ unsigned short packfp8(float a, float b){
  float ac = fminf(fmaxf(a, -448.f), 448.f);
  float bc = fminf(fmaxf(b, -448.f), 448.f);
  return (unsigned short)((unsigned)__builtin_amdgcn_cvt_pk_fp8_f32(ac, bc, 0, false) & 0xffffu);
}

// ---------------- weight pre-pack: transposed bf16 copies in workspace (L2-resident) ----------------
__global__ __launch_bounds__(256) void k_packall(
    const float* __restrict__ We2, const float* __restrict__ Wv, const float* __restrict__ Wo,
    const float* __restrict__ W1, const float* __restrict__ W2,
    const float* __restrict__ Wq, const float* __restrict__ Wk,
    const float* __restrict__ We1,
    unsigned short* we2t, unsigned short* wvt, unsigned short* wot,
    unsigned short* w1t, unsigned short* w2t, unsigned short* wqt, unsigned short* wkt,
    unsigned short* we1b){
  unsigned id = blockIdx.x*256 + threadIdx.x;   // pair index
  const unsigned PERL = 98304u;                  // pairs per layer
  if (id < 8192u){
    unsigned f = id & 127u, cp = id >> 7;
    *(unsigned*)&we2t[f*C + 2*cp] = pack2(We2[(2*cp)*C + f], We2[(2*cp+1)*C + f]);
    return;
  }
  unsigned rem = id - 8192u;
  unsigned layer = rem / PERL;
  if (layer >= 4u){
    unsigned r5 = rem - 4u*PERL;
    if (r5 < 38400u){
      unsigned r = r5 >> 6, cp = r5 & 63u;
      *(unsigned*)&we1b[r*C + 2*cp] = pack2(We1[(size_t)r*C + 2*cp], We1[(size_t)r*C + 2*cp + 1]);
    }
    return;
  }
  unsigned r2 = rem - layer*PERL;
  if (r2 < 32768u){
    unsigned mi = r2 >> 13;          // 0:Wv 1:Wo 2:W1 3:W2
    unsigned p = r2 & 8191u;
    unsigned f = p & 127u, cp = p >> 7;
    const float* S; unsigned short* D;
    if (mi==0){ S = Wv + (size_t)layer*C*C; D = wvt + (size_t)layer*16384; }
    else if (mi==1){ S = Wo + (size_t)layer*C*C; D = wot + (size_t)layer*16384; }
    else if (mi==2){ S = W1 + (size_t)layer*C*C; D = w1t + (size_t)layer*16384; }
    else { S = W2 + (size_t)layer*C*C; D = w2t + (size_t)layer*16384; }
    *(unsigned*)&D[f*C + 2*cp] = pack2(S[(2*cp)*C + f], S[(2*cp+1)*C + f]);
  } else {
    unsigned r3 = r2 - 32768u;       // 0..65535
    unsigned mi = r3 >> 15;          // 0: Wq, 1: Wk
    unsigned p = r3 & 32767u;
    unsigned f = p & 511u, cp = p >> 9;
    const float* S = (mi==0 ? Wq : Wk) + (size_t)layer*C*512;
    unsigned short* D = (mi==0 ? wqt : wkt) + (size_t)layer*65536;
    *(unsigned*)&D[(size_t)f*C + 2*cp] = pack2(S[(size_t)(2*cp)*512 + f], S[(size_t)(2*cp+1)*512 + f]);
  }
}

// ---------------- CSR build (bucketed by src-range) ----------------
__global__ void k_count(const int* tgt, const int* src, int* deg){
  int e = blockIdx.x*256 + threadIdx.x;
  if (e < N_EDGES){
    int b = (unsigned)src[e] / BUKW;
    atomicAdd(&deg[tgt[e]*NBUK + b], 1);
  }
}

// parallel exclusive scan: 1024 threads, 10 entries/thread, 2-level
__global__ __launch_bounds__(1024) void k_scan(const int* deg, int* rowptr){
  __shared__ int wsum[16];
  int t = threadIdx.x;
  int lane = t & 63, wv = t >> 6;
  const int CH = (N4 + 1023)/1024;      // 10
  int base = t*CH;
  int s = 0;
  #pragma unroll
  for (int i=0;i<CH;i++){ int idx=base+i; if (idx<N4) s += deg[idx]; }
  int inc = s;
  for (int d=1; d<64; d<<=1){
    int v = __shfl_up(inc, d, 64);
    if (lane >= d) inc += v;
  }
  if (lane == 63) wsum[wv] = inc;
  __syncthreads();
  int woff = 0;
  for (int i=0;i<wv;i++) woff += wsum[i];
  int run = woff + inc - s;
  #pragma unroll
  for (int i=0;i<CH;i++){
    int idx = base+i;
    if (idx < N4){ rowptr[idx] = run; run += deg[idx]; }
  }
  if (t == 1023) rowptr[N4] = woff + inc;
}

__global__ void k_fill(const int* tgt, const int* src, const int* rowptr, int* cursor,
                       int* elist, int2* epair){
  int e = blockIdx.x*256 + threadIdx.x;
  if (e < N_EDGES){
    int s = src[e];
    int b = (unsigned)s / BUKW;
    int slot_base = tgt[e]*NBUK + b;
    int pos = atomicAdd(&cursor[slot_base], 1);
    int slot = rowptr[slot_base] + pos;
    elist[slot] = e;
    int2 p; p.x = e; p.y = s;
    epair[slot] = p;
  }
}

// ---------------- edge features: 64 edges/block; GW=10 taps (bf16 We1); MFMA t1@we2t; OUT bf16 ----------------
__global__ __launch_bounds__(256) void k_efeat(const float* __restrict__ dist,
                                               const unsigned short* __restrict__ we1b,
                                               const unsigned short* __restrict__ we2t,
                                               unsigned short* __restrict__ efeat16){
  __shared__ float dsh[EB];
  __shared__ int j0s[EB];
  __shared__ int cns[EB];
  __shared__ __align__(16) unsigned short A16[EB*ASTR];   // 17408 B (t1 bf16)
  int t = threadIdx.x;
  int lane = t & 63;
  int e0 = blockIdx.x*EB;
  const float delta = 12.0f/599.0f;
  const float coeff = -0.5f/((2.0f*delta)*(2.0f*delta));
  if (t < EB){
    int e = e0 + t;
    float d = (e < N_EDGES) ? dist[e] : 0.f;
    int jc = (int)floorf(d/delta + 0.5f);
    int j0 = jc-GW; if (j0<0) j0=0;
    int j1 = jc+GW; if (j1>NB-1) j1=NB-1;
    dsh[t]=d; j0s[t]=j0; cns[t]=(e < N_EDGES)? (j1-j0+1) : 0;
  }
  __syncthreads();
  int hb = lane & 32;
  int myw = lane & 31;
  #pragma unroll
  for (int it=0; it<8; ++it){
    int task = t + (it<<8);
    int el = task >> 5, c4 = (task & 31)*4;
    float d = dsh[el]; int j0 = j0s[el]; int cn = cns[el];
    float gm = 0.f;
    if (myw < cn){
      float off = (float)(j0+myw)*delta;
      float dd = d-off;
      gm = __expf(coeff*dd*dd);
    }
    float a0=0.f,a1=0.f,a2=0.f,a3=0.f;
    for (int w=0; w<NTAP; ++w){
      float g = __shfl(gm, hb + w, 64);
      int row = j0+w; if (row > NB-1) row = NB-1;
      uint2 wv = *(const uint2*)&we1b[(size_t)row*C + c4];
      float2 w01 = bf2f2(wv.x);
      float2 w23 = bf2f2(wv.y);
      a0 += g*w01.x; a1 += g*w01.y; a2 += g*w23.x; a3 += g*w23.y;
    }
    *(unsigned*)&A16[el*ASTR + c4]     = pack2(silu(a0), silu(a1));
    *(unsigned*)&A16[el*ASTR + c4 + 2] = pack2(silu(a2), silu(a3));
  }
  __syncthreads();
  int w = t>>6;
  int lr = lane & 15, lg = lane >> 4;
  int colb = 32*w;
  f32x4 acc[4][2];
  #pragma unroll
  for (int rt=0;rt<4;rt++)
    #pragma unroll
    for (int ci=0;ci<2;ci++){ acc[rt][ci][0]=0.f; acc[rt][ci][1]=0.f; acc[rt][ci][2]=0.f; acc[rt][ci][3]=0.f; }
  #pragma unroll
  for (int ks=0; ks<4; ++ks){
    int k0 = ks*32 + lg*8;
    const unsigned short* Ab = &A16[lr*ASTR + k0];
    bf16x8 a0 = *(const bf16x8*)(Ab);
    bf16x8 a1 = *(const bf16x8*)(Ab + 16*ASTR);
    bf16x8 a2 = *(const bf16x8*)(Ab + 32*ASTR);
    bf16x8 a3 = *(const bf16x8*)(Ab + 48*ASTR);
    const unsigned short* Bb = &we2t[(colb + lr)*C + k0];
    bf16x8 b0 = *(const bf16x8*)(Bb);
    bf16x8 b1 = *(const bf16x8*)(Bb + 16*C);
    acc[0][0] = __builtin_amdgcn_mfma_f32_16x16x32_bf16(a0, b0, acc[0][0], 0, 0, 0);
    acc[1][0] = __builtin_amdgcn_mfma_f32_16x16x32_bf16(a1, b0, acc[1][0], 0, 0, 0);
    acc[2][0] = __builtin_amdgcn_mfma_f32_16x16x32_bf16(a2, b0, acc[2][0], 0, 0, 0);
    acc[3][0] = __builtin_amdgcn_mfma_f32_16x16x32_bf16(a3, b0, acc[3][0], 0, 0, 0);
    acc[0][1] = __builtin_amdgcn_mfma_f32_16x16x32_bf16(a0, b1, acc[0][1], 0, 0, 0);
    acc[1][1] = __builtin_amdgcn_mfma_f32_16x16x32_bf16(a1, b1, acc[1][1], 0, 0, 0);
    acc[2][1] = __builtin_amdgcn_mfma_f32_16x16x32_bf16(a2, b1, acc[2][1], 0, 0, 0);
    acc[3][1] = __builtin_amdgcn_mfma_f32_16x16x32_bf16(a3, b1, acc[3][1], 0, 0, 0);
  }
  #pragma unroll
  for (int rt=0;rt<4;rt++){
    #pragma unroll
    for (int ci=0;ci<2;ci++){
      int col = colb + 16*ci + lr;
      #pragma unroll
      for (int q=0;q<4;q++){
        int r = 16*rt + lg*4 + q;
        int e = e0 + r;
        if (e < N_EDGES)
          efeat16[(size_t)e*C + col] = bf16of(silu(acc[rt][ci][q]));
      }
    }
  }
}

// efsumT[c][n]  (reads bf16 efeat)
__global__ void k_efsum(const unsigned short* efeat16, const int* rowptr, const int* elist, float* efsumT){
  int n = blockIdx.x; int t = threadIdx.x; // 128 threads
  float acc = 0.f;
  int beg = rowptr[n*NBUK], end = rowptr[n*NBUK+NBUK];
  for (int i=beg;i<end;i++)
    acc += bf2f(efeat16[(size_t)elist[i]*C + t]);
  efsumT[(size_t)t*N_NODES + n] = acc;
}

// ---------------- deg-init ----------------
__global__ __launch_bounds__(256) void k_deginit(const float* __restrict__ efsumT, const float* __restrict__ Wdeg,
        const float* __restrict__ emb, const int* __restrict__ anum, float* __restrict__ x){
  __shared__ __align__(16) float efT[C][16];
  int t = threadIdx.x;
  int n0 = blockIdx.x*16;
  int grp = blockIdx.y;
  for (int q=t; q<16*C; q+=256){
    int cc=q>>4, nd=q&15;
    int n=n0+nd;
    efT[cc][nd] = (n<N_NODES)? efsumT[(size_t)cc*N_NODES + n] : 0.f;
  }
  __syncthreads();
  const float inv_avg = 1.0f/23.395238876342773f;
  int o = grp*512 + t*2;
  if (o < MC*C){
    float a0[16], a1[16];
    #pragma unroll
    for (int i=0;i<16;i++){ a0[i]=0.f; a1[i]=0.f; }
    for (int cc=0; cc<C; ++cc){
      float2 w = *(const float2*)&Wdeg[(size_t)cc*(MC*C)+o];
      float4 e0 = *(const float4*)&efT[cc][0];
      float4 e1 = *(const float4*)&efT[cc][4];
      float4 e2 = *(const float4*)&efT[cc][8];
      float4 e3 = *(const float4*)&efT[cc][12];
      a0[0]+=e0.x*w.x; a1[0]+=e0.x*w.y;
      a0[1]+=e0.y*w.x; a1[1]+=e0.y*w.y;
      a0[2]+=e0.z*w.x; a1[2]+=e0.z*w.y;
      a0[3]+=e0.w*w.x; a1[3]+=e0.w*w.y;
      a0[4]+=e1.x*w.x; a1[4]+=e1.x*w.y;
      a0[5]+=e1.y*w.x; a1[5]+=e1.y*w.y;
      a0[6]+=e1.z*w.x; a1[6]+=e1.z*w.y;
      a0[7]+=e1.w*w.x; a1[7]+=e1.w*w.y;
      a0[8]+=e2.x*w.x; a1[8]+=e2.x*w.y;
      a0[9]+=e2.y*w.x; a1[9]+=e2.y*w.y;
      a0[10]+=e2.z*w.x; a1[10]+=e2.z*w.y;
      a0[11]+=e2.w*w.x; a1[11]+=e2.w*w.y;
      a0[12]+=e3.x*w.x; a1[12]+=e3.x*w.y;
      a0[13]+=e3.y*w.x; a1[13]+=e3.y*w.y;
      a0[14]+=e3.z*w.x; a1[14]+=e3.z*w.y;
      a0[15]+=e3.w*w.x; a1[15]+=e3.w*w.y;
    }
    #pragma unroll
    for (int nd=0; nd<16; ++nd){
      int n = n0+nd;
      if (n < N_NODES){
        float v0 = a0[nd]*inv_avg, v1 = a1[nd]*inv_avg;
        if (o < C){ int an=anum[n]; v0 += emb[an*C+o]; v1 += emb[an*C+o+1]; }
        float2 st; st.x=v0; st.y=v1;
        *(float2*)&x[(size_t)n*MC*C + o] = st;
      }
    }
  }
}

// ---------------- FUSED nodeA (rmsnorm1+V, blocks 0..624) + QK proj (blocks 625..1256) ----------------
__global__ __launch_bounds__(256) void k_nAqk(const float* __restrict__ x, const float* __restrict__ scale0,
        const unsigned short* __restrict__ wvt, const unsigned short* __restrict__ wqt,
        const unsigned short* __restrict__ wkt,
        unsigned char* __restrict__ V, unsigned short* __restrict__ qb, unsigned short* __restrict__ kb){
  __shared__ __align__(16) char smem[26880];
  int t = threadIdx.x;
  int w = t>>6, lane = t&63;
  int lr = lane & 15, lg = lane >> 4;
  if (blockIdx.x < (unsigned)(N_NODES/4)){
    // ================= nodeA =================
    unsigned short* A16 = (unsigned short*)smem;    // 80*ASTR
    int n0 = blockIdx.x*4;
    {
      int n = n0 + w;
      float2 xv[MC];
      float pl[5]={0.f,0.f,0.f,0.f,0.f};
      #pragma unroll
      for (int m=0;m<MC;m++){
        float2 v = *(const float2*)&x[(size_t)n*MC*C + m*C + lane*2];
        xv[m]=v;
        pl[l_of_m(m)] += v.x*v.x + v.y*v.y;
      }
      #pragma unroll
      for (int l=0;l<5;l++){
        float r = pl[l];
        #pragma unroll
        for (int d=32; d>0; d>>=1) r += __shfl_xor(r, d, 64);
        pl[l]=r;
      }
      const float dens[5] = {128.f,384.f,640.f,896.f,1152.f};
      float inv[5];
      #pragma unroll
      for (int l=0;l<5;l++) inv[l] = 1.0f/sqrtf(pl[l]/dens[l] + 1e-8f);
      #pragma unroll
      for (int m=0;m<MC;m++){
        int l = l_of_m(m);
        float2 sc = *(const float2*)&scale0[l*C + lane*2];
        float a = xv[m].x*inv[l]*sc.x, b = xv[m].y*inv[l]*sc.y;
        *(unsigned*)&A16[(w*MC + m)*ASTR + lane*2] = pack2(a, b);
      }
    }
    for (int q=t; q<272; q+=256)
      ((unsigned*)A16)[(76*ASTR)/2 + q] = 0u;
    __syncthreads();
    int colb = 32*w;
    f32x4 acc[5][2];
    #pragma unroll
    for (int rt=0;rt<5;rt++)
      #pragma unroll
      for (int ci=0;ci<2;ci++){ acc[rt][ci][0]=0.f; acc[rt][ci][1]=0.f; acc[rt][ci][2]=0.f; acc[rt][ci][3]=0.f; }
    #pragma unroll
    for (int ks=0; ks<4; ++ks){
      int k0 = ks*32 + lg*8;
      const unsigned short* Ab = &A16[lr*ASTR + k0];
      bf16x8 a0 = *(const bf16x8*)(Ab);
      bf16x8 a1 = *(const bf16x8*)(Ab + 16*ASTR);
      bf16x8 a2 = *(const bf16x8*)(Ab + 32*ASTR);
      bf16x8 a3 = *(const bf16x8*)(Ab + 48*ASTR);
      bf16x8 a4 = *(const bf16x8*)(Ab + 64*ASTR);
      const unsigned short* Bb = &wvt[(colb + lr)*C + k0];
      bf16x8 b0 = *(const bf16x8*)(Bb);
      bf16x8 b1 = *(const bf16x8*)(Bb + 16*C);
      acc[0][0] = __builtin_amdgcn_mfma_f32_16x16x32_bf16(a0, b0, acc[0][0], 0, 0, 0);
      acc[1][0] = __builtin_amdgcn_mfma_f32_16x16x32_bf16(a1, b0, acc[1][0], 0, 0, 0);
      acc[2][0] = __builtin_amdgcn_mfma_f32_16x16x32_bf16(a2, b0, acc[2][0], 0, 0, 0);
      acc[3][0] = __builtin_amdgcn_mfma_f32_16x16x32_bf16(a3, b0, acc[3][0], 0, 0, 0);
      acc[4][0] = __builtin_amdgcn_mfma_f32_16x16x32_bf16(a4, b0, acc[4][0], 0, 0, 0);
      acc[0][1] = __builtin_amdgcn_mfma_f32_16x16x32_bf16(a0, b1, acc[0][1], 0, 0, 0);
      acc[1][1] = __builtin_amdgcn_mfma_f32_16x16x32_bf16(a1, b1, acc[1][1], 0, 0, 0);
      acc[2][1] = __builtin_amdgcn_mfma_f32_16x16x32_bf16(a2, b1, acc[2][1], 0, 0, 0);
      acc[3][1] = __builtin_amdgcn_mfma_f32_16x16x32_bf16(a3, b1, acc[3][1], 0, 0, 0);
      acc[4][1] = __builtin_amdgcn_mfma_f32_16x16x32_bf16(a4, b1, acc[4][1], 0, 0, 0);
    }
    __syncthreads();
    #pragma unroll
    for (int rt=0;rt<5;rt++){
      #pragma unroll
      for (int ci=0;ci<2;ci++){
        int col = colb + 16*ci + lr;
        #pragma unroll
        for (int q=0;q<4;q++){
          int r = 16*rt + lg*4 + q;
          A16[r*ASTR + col] = bf16of(acc[rt][ci][q]);
        }
      }
    }
    __syncthreads();
    for (int q=t; q<76*64; q+=256){
      int r = q>>6;
      int c2 = (q&63)*2;
      unsigned u = *(unsigned*)&A16[r*ASTR + c2];
      float2 f = bf2f2(u);
      *(unsigned short*)&V[((size_t)(n0*MC + r))*C + c2] = packfp8(f.x, f.y);
    }
  } else {
    // ================= QK =================
    int qq = blockIdx.x - N_NODES/4;
    int grp = qq / NQKB;
    int n0 = (qq - grp*NQKB)*32;
    float (*sn)[132] = (float(*)[132])smem;                     // 16896 B
    float (*ps)[8] = (float(*)[8])(smem + 16896);               // 1024 B
    float* invs = (float*)(smem + 16896 + 1024);                // 128 B
    unsigned short* A16 = (unsigned short*)(smem + 16896 + 1024 + 128);  // 8704 B
    const unsigned short* WTg = (grp < 4) ? wqt : wkt;
    int cb = (grp & 3)*128;
    unsigned short* outb = (grp < 4) ? qb : kb;
    {
      int nd = t>>3, seg = t&7;
      int n = n0+nd;
      float ss = 0.f;
      if (n < N_NODES){
        const float* xr = &x[(size_t)n*MC*C];
        #pragma unroll
        for (int i=0;i<16;i++){
          int c = seg*16+i;
          float v = xr[c];
          ss += v*v;
          sn[nd][c] = v*scale0[c];
        }
      } else {
        #pragma unroll
        for (int i=0;i<16;i++) sn[nd][seg*16+i] = 0.f;
      }
      ps[nd][seg] = ss;
    }
    __syncthreads();
    if (t < 32){
      float s = 0.f;
      #pragma unroll
      for (int i=0;i<8;i++) s += ps[t][i];
      invs[t] = 1.0f/sqrtf(s*(1.0f/128.f) + 1e-8f);
    }
    __syncthreads();
    for (int q=t; q<32*64; q+=256){
      int r = q>>6, c2 = (q&63)*2;
      float inv = invs[r];
      *(unsigned*)&A16[r*ASTR + c2] = pack2(sn[r][c2]*inv, sn[r][c2+1]*inv);
    }
    __syncthreads();
    int colb = 32*w;
    f32x4 acc[2][2];
    #pragma unroll
    for (int rt=0;rt<2;rt++)
      #pragma unroll
      for (int ci=0;ci<2;ci++){ acc[rt][ci][0]=0.f; acc[rt][ci][1]=0.f; acc[rt][ci][2]=0.f; acc[rt][ci][3]=0.f; }
    #pragma unroll
    for (int ks=0; ks<4; ++ks){
      int k0 = ks*32 + lg*8;
      const unsigned short* Ab = &A16[lr*ASTR + k0];
      bf16x8 a0 = *(const bf16x8*)(Ab);
      bf16x8 a1 = *(const bf16x8*)(Ab + 16*ASTR);
      const unsigned short* Bb = &WTg[(size_t)(cb + colb + lr)*C + k0];
      bf16x8 b0 = *(const bf16x8*)(Bb);
      bf16x8 b1 = *(const bf16x8*)(Bb + 16*C);
      acc[0][0] = __builtin_amdgcn_mfma_f32_16x16x32_bf16(a0, b0, acc[0][0], 0, 0, 0);
      acc[1][0] = __builtin_amdgcn_mfma_f32_16x16x32_bf16(a1, b0, acc[1][0], 0, 0, 0);
      acc[0][1] = __builtin_amdgcn_mfma_f32_16x16x32_bf16(a0, b1, acc[0][1], 0, 0, 0);
      acc[1][1] = __builtin_amdgcn_mfma_f32_16x16x32_bf16(a1, b1, acc[1][1], 0, 0, 0);
    }
    #pragma unroll
    for (int rt=0;rt<2;rt++){
      #pragma unroll
      for (int ci=0;ci<2;ci++){
        int col = colb + 16*ci + lr;
        #pragma unroll
        for (int q=0;q<4;q++){
          int r = 16*rt + lg*4 + q;
          int n = n0 + r;
          if (n < N_NODES)
            outb[(size_t)n*512 + cb + col] = bf16of(acc[rt][ci][q]);
        }
      }
    }
  }
}

// ---------------- FUSED attn (blocks 0..624) + rad (blocks 625..1406) ----------------
// rad: A-fragments DIRECT from global bf16 efeat16 (no LDS staging)
__global__ __launch_bounds__(256) void k_attnrad(const unsigned short* __restrict__ qb,
        const unsigned short* __restrict__ kb, const float* __restrict__ alpha,
        const int* __restrict__ rowptr, const int2* __restrict__ epair, float* __restrict__ attnb,
        const unsigned short* __restrict__ efeat16, const float* __restrict__ Wrad,
        float* __restrict__ radb){
  __shared__ __align__(16) char smem[13824];
  int t = threadIdx.x;
  int w = t>>6, lane = t&63;
  if (blockIdx.x < (unsigned)(N_NODES/4)){
    // ================= attn =================
    float (*lw)[MAXE][8] = (float(*)[MAXE][8])smem;     // 12288 B
    int (*eid)[MAXE] = (int(*)[MAXE])(smem + 12288);    // 1536 B
    int n = blockIdx.x*4 + w;
    float al[8];
    {
      float4 a0 = *(const float4*)&alpha[lane*8];
      float4 a1 = *(const float4*)&alpha[lane*8+4];
      al[0]=a0.x; al[1]=a0.y; al[2]=a0.z; al[3]=a0.w;
      al[4]=a1.x; al[5]=a1.y; al[6]=a1.z; al[7]=a1.w;
    }
    float qf[8];
    {
      int4 qv = *(const int4*)&qb[(size_t)n*512 + lane*8];
      unsigned qu[4] = {(unsigned)qv.x,(unsigned)qv.y,(unsigned)qv.z,(unsigned)qv.w};
      #pragma unroll
      for (int j=0;j<4;j++){
        float2 q2 = bf2f2(qu[j]);
        qf[2*j] = q2.x; qf[2*j+1] = q2.y;
      }
    }
    int beg = rowptr[n*NBUK], end = rowptr[n*NBUK+NBUK];
    int cnt = end - beg; if (cnt > MAXE) cnt = MAXE;
    int i = 0;
    for (; i+4 <= cnt; i += 4){
      int2 p0 = epair[beg+i];
      int2 p1 = epair[beg+i+1];
      int2 p2 = epair[beg+i+2];
      int2 p3 = epair[beg+i+3];
      int4 kv0 = *(const int4*)&kb[(size_t)p0.y*512 + lane*8];
      int4 kv1 = *(const int4*)&kb[(size_t)p1.y*512 + lane*8];
      int4 kv2 = *(const int4*)&kb[(size_t)p2.y*512 + lane*8];
      int4 kv3 = *(const int4*)&kb[(size_t)p3.y*512 + lane*8];
      unsigned ku0[4] = {(unsigned)kv0.x,(unsigned)kv0.y,(unsigned)kv0.z,(unsigned)kv0.w};
      unsigned ku1[4] = {(unsigned)kv1.x,(unsigned)kv1.y,(unsigned)kv1.z,(unsigned)kv1.w};
      unsigned ku2[4] = {(unsigned)kv2.x,(unsigned)kv2.y,(unsigned)kv2.z,(unsigned)kv2.w};
      unsigned ku3[4] = {(unsigned)kv3.x,(unsigned)kv3.y,(unsigned)kv3.z,(unsigned)kv3.w};
      float acc0 = 0.f, acc1 = 0.f, acc2 = 0.f, acc3 = 0.f;
      #pragma unroll
      for (int j=0;j<4;j++){
        float2 k0 = bf2f2(ku0[j]);
        float2 k1 = bf2f2(ku1[j]);
        float2 k2 = bf2f2(ku2[j]);
        float2 k3 = bf2f2(ku3[j]);
        acc0 += silu(qf[2*j]+k0.x)*al[2*j] + silu(qf[2*j+1]+k0.y)*al[2*j+1];
        acc1 += silu(qf[2*j]+k1.x)*al[2*j] + silu(qf[2*j+1]+k1.y)*al[2*j+1];
        acc2 += silu(qf[2*j]+k2.x)*al[2*j] + silu(qf[2*j+1]+k2.y)*al[2*j+1];
        acc3 += silu(qf[2*j]+k3.x)*al[2*j] + silu(qf[2*j+1]+k3.y)*al[2*j+1];
      }
      #pragma unroll
      for (int d=1; d<8; d<<=1){
        acc0 += __shfl_down(acc0, d, 64);
        acc1 += __shfl_down(acc1, d, 64);
        acc2 += __shfl_down(acc2, d, 64);
        acc3 += __shfl_down(acc3, d, 64);
      }
      if ((lane&7)==0){
        lw[w][i][lane>>3]   = acc0 * 0.125f;
        lw[w][i+1][lane>>3] = acc1 * 0.125f;
        lw[w][i+2][lane>>3] = acc2 * 0.125f;
        lw[w][i+3][lane>>3] = acc3 * 0.125f;
      }
      if (lane==0){
        eid[w][i] = p0.x; eid[w][i+1] = p1.x;
        eid[w][i+2] = p2.x; eid[w][i+3] = p3.x;
      }
    }
    for (; i < cnt; ++i){
      int2 p0 = epair[beg+i];
      int4 kv0 = *(const int4*)&kb[(size_t)p0.y*512 + lane*8];
      unsigned ku0[4] = {(unsigned)kv0.x,(unsigned)kv0.y,(unsigned)kv0.z,(unsigned)kv0.w};
      float acc0 = 0.f;
      #pragma unroll
      for (int j=0;j<4;j++){
        float2 k0 = bf2f2(ku0[j]);
        acc0 += silu(qf[2*j]+k0.x)*al[2*j] + silu(qf[2*j+1]+k0.y)*al[2*j+1];
      }
      #pragma unroll
      for (int d=1; d<8; d<<=1) acc0 += __shfl_down(acc0, d, 64);
      if ((lane&7)==0) lw[w][i][lane>>3] = acc0 * 0.125f;
      if (lane==0) eid[w][i] = p0.x;
    }
    __syncthreads();
    int h = lane & 7, ec = lane >> 3;
    float mx = -1e30f;
    for (int q=ec; q<cnt; q+=8) mx = fmaxf(mx, lw[w][q][h]);
    #pragma unroll
    for (int dd=8; dd<64; dd<<=1) mx = fmaxf(mx, __shfl_xor(mx, dd, 64));
    float sum = 0.f;
    for (int q=ec; q<cnt; q+=8) sum += __expf(lw[w][q][h] - mx);
    #pragma unroll
    for (int dd=8; dd<64; dd<<=1) sum += __shfl_xor(sum, dd, 64);
    float inv = 1.0f/(sum + 1e-9f);
    for (int q=ec; q<cnt; q+=8)
      attnb[eid[w][q]*8 + h] = __expf(lw[w][q][h] - mx) * inv;
  } else {
    // ================= rad (A direct from global bf16) =================
    unsigned short* WT = (unsigned short*)smem;              // 32*ASTR*2 = 8704
    int e0 = (blockIdx.x - N_NODES/4)*EB;
    for (int q=t; q<32*64; q+=256){
      int m = q>>6, c2 = (q&63)*2;
      float w0 = (m < MC) ? Wrad[(size_t)c2*MC + m] : 0.f;
      float w1 = (m < MC) ? Wrad[(size_t)(c2+1)*MC + m] : 0.f;
      *(unsigned*)&WT[m*ASTR + c2] = pack2(w0, w1);
    }
    __syncthreads();
    int lr = lane & 15, lg = lane >> 4;
    f32x4 acc[2];
    acc[0][0]=0.f; acc[0][1]=0.f; acc[0][2]=0.f; acc[0][3]=0.f;
    acc[1][0]=0.f; acc[1][1]=0.f; acc[1][2]=0.f; acc[1][3]=0.f;
    const unsigned short* Ag = &efeat16[(size_t)(e0 + 16*w + lr)*C];
    #pragma unroll
    for (int ks=0; ks<4; ++ks){
      int k0 = ks*32 + lg*8;
      bf16x8 a  = *(const bf16x8*)(Ag + k0);
      bf16x8 b0 = *(const bf16x8*)&WT[lr*ASTR + k0];
      bf16x8 b1 = *(const bf16x8*)&WT[(16+lr)*ASTR + k0];
      acc[0] = __builtin_amdgcn_mfma_f32_16x16x32_bf16(a, b0, acc[0], 0, 0, 0);
      acc[1] = __builtin_amdgcn_mfma_f32_16x16x32_bf16(a, b1, acc[1], 0, 0, 0);
    }
    #pragma unroll
    for (int ci=0;ci<2;ci++){
      int m = 16*ci + lr;
      #pragma unroll
      for (int q=0;q<4;q++){
        int r = 16*w + lg*4 + q;
        int e = e0 + r;
        if (m < MC && e < N_EDGES)
          radb[(size_t)e*RSTR + m] = silu(acc[ci][q]);
      }
    }
  }
}

// msum[n,m,d] = sum_e attn*rad*V (V fp8 e4m3); MFMA Wo epilogue with B direct from wot
#define CONS1(vv, ar)  { \
    floatx2 g0 = __builtin_amdgcn_cvt_pk_f32_fp8((vv).x, false); \
    floatx2 g1 = __builtin_amdgcn_cvt_pk_f32_fp8((vv).x, true);  \
    floatx2 g2 = __builtin_amdgcn_cvt_pk_f32_fp8((vv).y, false); \
    floatx2 g3 = __builtin_amdgcn_cvt_pk_f32_fp8((vv).y, true);  \
    acc1[0] += (ar)*g0[0]; acc1[1] += (ar)*g0[1]; \
    acc1[2] += (ar)*g1[0]; acc1[3] += (ar)*g1[1]; \
    acc1[4] += (ar)*g2[0]; acc1[5] += (ar)*g2[1]; \
    acc1[6] += (ar)*g3[0]; acc1[7] += (ar)*g3[1]; }
#define CONS2(vv, ar)  { \
    floatx2 g0 = __builtin_amdgcn_cvt_pk_f32_fp8((vv).x, false); \
    floatx2 g1 = __builtin_amdgcn_cvt_pk_f32_fp8((vv).x, true);  \
    floatx2 g2 = __builtin_amdgcn_cvt_pk_f32_fp8((vv).y, false); \
    floatx2 g3 = __builtin_amdgcn_cvt_pk_f32_fp8((vv).y, true);  \
    acc2[0] += (ar)*g0[0]; acc2[1] += (ar)*g0[1]; \
    acc2[2] += (ar)*g1[0]; acc2[3] += (ar)*g1[1]; \
    acc2[4] += (ar)*g2[0]; acc2[5] += (ar)*g2[1]; \
    acc2[6] += (ar)*g3[0]; acc2[7] += (ar)*g3[1]; }
__global__ __launch_bounds__(256, 4) void k_e1(const unsigned char* __restrict__ V, const float* __restrict__ radb,
        const float* __restrict__ attnb, const unsigned short* __restrict__ wot,
        const int* __restrict__ rowptr, const int2* __restrict__ epair,
        float* __restrict__ x){
  __shared__ __align__(16) float msum[32*MSTR];           // 16896 B (rows 19..31 zero)
  int n = blockIdx.x;
  int t = threadIdx.x;
  int w = t>>6, lane = t&63;
  for (int q=t; q<13*MSTR; q+=256) msum[19*MSTR + q] = 0.f;
  int chunk = lane & 15;
  int g = lane >> 4;
  int m1 = w*5 + g;
  int c1 = chunk*8;
  int h1 = chunk>>1;
  int m2 = w*5 + 4;
  bool has2 = (w < 3) && (lane < 16);
  int voff1 = m1*C + c1;
  int voff2 = m2*C + lane*8;
  int h2 = lane>>1;
  float acc1[8], acc2[8];
  #pragma unroll
  for (int j=0;j<8;j++){ acc1[j]=0.f; acc2[j]=0.f; }
  int beg = rowptr[n*NBUK], end = rowptr[n*NBUK+NBUK];
  int idx = beg;
  for (; idx+4 <= end; idx += 4){
    int2 p0 = epair[idx];
    int2 p1 = epair[idx+1];
    int2 p2 = epair[idx+2];
    int2 p3 = epair[idx+3];
    const unsigned char* vb0 = V + (size_t)p0.y*(MC*C);
    const unsigned char* vb1 = V + (size_t)p1.y*(MC*C);
    const unsigned char* vb2 = V + (size_t)p2.y*(MC*C);
    const unsigned char* vb3 = V + (size_t)p3.y*(MC*C);
    int2 va0 = *(const int2*)(vb0 + voff1);
    int2 va1 = *(const int2*)(vb1 + voff1);
    int2 va2 = *(const int2*)(vb2 + voff1);
    int2 va3 = *(const int2*)(vb3 + voff1);
    float ra0 = attnb[p0.x*8 + h1] * radb[(size_t)p0.x*RSTR + m1];
    float ra1 = attnb[p1.x*8 + h1] * radb[(size_t)p1.x*RSTR + m1];
    float ra2 = attnb[p2.x*8 + h1] * radb[(size_t)p2.x*RSTR + m1];
    float ra3 = attnb[p3.x*8 + h1] * radb[(size_t)p3.x*RSTR + m1];
    int2 wa0, wa1, wa2, wa3;
    float qa0=0.f, qa1=0.f, qa2=0.f, qa3=0.f;
    if (has2){
      wa0 = *(const int2*)(vb0 + voff2);
      wa1 = *(const int2*)(vb1 + voff2);
      wa2 = *(const int2*)(vb2 + voff2);
      wa3 = *(const int2*)(vb3 + voff2);
      qa0 = attnb[p0.x*8 + h2] * radb[(size_t)p0.x*RSTR + m2];
      qa1 = attnb[p1.x*8 + h2] * radb[(size_t)p1.x*RSTR + m2];
      qa2 = attnb[p2.x*8 + h2] * radb[(size_t)p2.x*RSTR + m2];
      qa3 = attnb[p3.x*8 + h2] * radb[(size_t)p3.x*RSTR + m2];
    }
    CONS1(va0, ra0);
    CONS1(va1, ra1);
    CONS1(va2, ra2);
    CONS1(va3, ra3);
    if (has2){
      CONS2(wa0, qa0);
      CONS2(wa1, qa1);
      CONS2(wa2, qa2);
      CONS2(wa3, qa3);
    }
  }
  for (; idx < end; ++idx){
    int2 p0 = epair[idx];
    const unsigned char* vb = V + (size_t)p0.y*(MC*C);
    int2 va = *(const int2*)(vb + voff1);
    float ra = attnb[p0.x*8 + h1] * radb[(size_t)p0.x*RSTR + m1];
    int2 wa; float qa = 0.f;
    if (has2){
      wa = *(const int2*)(vb + voff2);
      qa = attnb[p0.x*8 + h2] * radb[(size_t)p0.x*RSTR + m2];
    }
    CONS1(va, ra);
    if (has2){ CONS2(wa, qa); }
  }
  {
    float4 st0; st0.x=acc1[0]; st0.y=acc1[1]; st0.z=acc1[2]; st0.w=acc1[3];
    float4 st1; st1.x=acc1[4]; st1.y=acc1[5]; st1.z=acc1[6]; st1.w=acc1[7];
    *(float4*)&msum[m1*MSTR + c1]     = st0;
    *(float4*)&msum[m1*MSTR + c1 + 4] = st1;
    if (has2){
      float4 s2a; s2a.x=acc2[0]; s2a.y=acc2[1]; s2a.z=acc2[2]; s2a.w=acc2[3];
      float4 s2b; s2b.x=acc2[4]; s2b.y=acc2[5]; s2b.z=acc2[6]; s2b.w=acc2[7];
      *(float4*)&msum[m2*MSTR + lane*8]     = s2a;
      *(float4*)&msum[m2*MSTR + lane*8 + 4] = s2b;
    }
  }
  __syncthreads();
  int lr = lane & 15, lg = lane >> 4;
  int colb = 32*w;
  f32x4 eacc[2][2];
  #pragma unroll
  for (int rt=0;rt<2;rt++)
    #pragma unroll
    for (int ci=0;ci<2;ci++){ eacc[rt][ci][0]=0.f; eacc[rt][ci][1]=0.f; eacc[rt][ci][2]=0.f; eacc[rt][ci][3]=0.f; }
  #pragma unroll
  for (int ks=0; ks<4; ++ks){
    int k0 = ks*32 + lg*8;
    float4 a0lo = *(const float4*)&msum[lr*MSTR + k0];
    float4 a0hi = *(const float4*)&msum[lr*MSTR + k0 + 4];
    float4 a1lo = *(const float4*)&msum[(lr+16)*MSTR + k0];
    float4 a1hi = *(const float4*)&msum[(lr+16)*MSTR + k0 + 4];
    bf16x8 a0 = packbf8(a0lo, a0hi);
    bf16x8 a1 = packbf8(a1lo, a1hi);
    const unsigned short* Bb = &wot[(colb + lr)*C + k0];
    bf16x8 b0 = *(const bf16x8*)(Bb);
    bf16x8 b1 = *(const bf16x8*)(Bb + 16*C);
    eacc[0][0] = __builtin_amdgcn_mfma_f32_16x16x32_bf16(a0, b0, eacc[0][0], 0, 0, 0);
    eacc[1][0] = __builtin_amdgcn_mfma_f32_16x16x32_bf16(a1, b0, eacc[1][0], 0, 0, 0);
    eacc[0][1] = __builtin_amdgcn_mfma_f32_16x16x32_bf16(a0, b1, eacc[0][1], 0, 0, 0);
    eacc[1][1] = __builtin_amdgcn_mfma_f32_16x16x32_bf16(a1, b1, eacc[1][1], 0, 0, 0);
  }
  #pragma unroll
  for (int rt=0;rt<2;rt++){
    #pragma unroll
    for (int ci=0;ci<2;ci++){
      int col = colb + 16*ci + lr;
      #pragma unroll
      for (int q=0;q<4;q++){
        int r = 16*rt + lg*4 + q;
        if (r < MC){
          size_t off = (size_t)n*MC*C + r*C + col;
          x[off] += eacc[rt][ci][q];
        }
      }
    }
  }
}

// ---------------- rmsnorm2 + gated FFN via MFMA, 4 nodes/block; B direct from w1t/w2t ----------------
__global__ __launch_bounds__(256) void k_nodeB(float* __restrict__ x, const float* __restrict__ scale,
        const unsigned short* __restrict__ w1t, const unsigned short* __restrict__ w2t){
  __shared__ __align__(16) unsigned short A16[80*ASTR];   // 21760 B (A, then hb)
  __shared__ float gate[4*C];                             // 2048 B
  int t = threadIdx.x;
  int n0 = blockIdx.x*4;
  int w = t>>6, lane = t&63;
  int lr = lane & 15, lg = lane >> 4;
  {
    int n = n0 + w;
    float2 xv[MC];
    float pl[5]={0.f,0.f,0.f,0.f,0.f};
    #pragma unroll
    for (int m=0;m<MC;m++){
      float2 v = *(const float2*)&x[(size_t)n*MC*C + m*C + lane*2];
      xv[m]=v;
      pl[l_of_m(m)] += v.x*v.x + v.y*v.y;
    }
    #pragma unroll
    for (int l=0;l<5;l++){
      float r = pl[l];
      #pragma unroll
      for (int d=32; d>0; d>>=1) r += __shfl_xor(r, d, 64);
      pl[l]=r;
    }
    const float dens[5] = {128.f,384.f,640.f,896.f,1152.f};
    float inv[5];
    #pragma unroll
    for (int l=0;l<5;l++) inv[l] = 1.0f/sqrtf(pl[l]/dens[l] + 1e-8f);
    #pragma unroll
    for (int m=0;m<MC;m++){
      int l = l_of_m(m);
      float2 sc = *(const float2*)&scale[l*C + lane*2];
      float a = xv[m].x*inv[l]*sc.x, b = xv[m].y*inv[l]*sc.y;
      *(unsigned*)&A16[(w*MC + m)*ASTR + lane*2] = pack2(a, b);
    }
  }
  for (int q=t; q<272; q+=256)
    ((unsigned*)A16)[(76*ASTR)/2 + q] = 0u;
  __syncthreads();
  int colb = 32*w;
  f32x4 acc[5][2];
  #pragma unroll
  for (int rt=0;rt<5;rt++)
    #pragma unroll
    for (int ci=0;ci<2;ci++){ acc[rt][ci][0]=0.f; acc[rt][ci][1]=0.f; acc[rt][ci][2]=0.f; acc[rt][ci][3]=0.f; }
  #pragma unroll
  for (int ks=0; ks<4; ++ks){
    int k0 = ks*32 + lg*8;
    const unsigned short* Ab = &A16[lr*ASTR + k0];
    bf16x8 a0 = *(const bf16x8*)(Ab);
    bf16x8 a1 = *(const bf16x8*)(Ab + 16*ASTR);
    bf16x8 a2 = *(const bf16x8*)(Ab + 32*ASTR);
    bf16x8 a3 = *(const bf16x8*)(Ab + 48*ASTR);
    bf16x8 a4 = *(const bf16x8*)(Ab + 64*ASTR);
    const unsigned short* Bb = &w1t[(colb + lr)*C + k0];
    bf16x8 b0 = *(const bf16x8*)(Bb);
    bf16x8 b1 = *(const bf16x8*)(Bb + 16*C);
    acc[0][0] = __builtin_amdgcn_mfma_f32_16x16x32_bf16(a0, b0, acc[0][0], 0, 0, 0);
    acc[1][0] = __builtin_amdgcn_mfma_f32_16x16x32_bf16(a1, b0, acc[1][0], 0, 0, 0);
    acc[2][0] = __builtin_amdgcn_mfma_f32_16x16x32_bf16(a2, b0, acc[2][0], 0, 0, 0);
    acc[3][0] = __builtin_amdgcn_mfma_f32_16x16x32_bf16(a3, b0, acc[3][0], 0, 0, 0);
    acc[4][0] = __builtin_amdgcn_mfma_f32_16x16x32_bf16(a4, b0, acc[4][0], 0, 0, 0);
    acc[0][1] = __builtin_amdgcn_mfma_f32_16x16x32_bf16(a0, b1, acc[0][1], 0, 0, 0);
    acc[1][1] = __builtin_amdgcn_mfma_f32_16x16x32_bf16(a1, b1, acc[1][1], 0, 0, 0);
    acc[2][1] = __builtin_amdgcn_mfma_f32_16x16x32_bf16(a2, b1, acc[2][1], 0, 0, 0);
    acc[3][1] = __builtin_amdgcn_mfma_f32_16x16x32_bf16(a3, b1, acc[3][1], 0, 0, 0);
    acc[4][1] = __builtin_amdgcn_mfma_f32_16x16x32_bf16(a4, b1, acc[4][1], 0, 0, 0);
  }
  __syncthreads();
  #pragma unroll
  for (int rt=0;rt<5;rt++){
    #pragma unroll
    for (int ci=0;ci<2;ci++){
      int col = colb + 16*ci + lr;
      #pragma unroll
      for (int q=0;q<4;q++){
        int r = 16*rt + lg*4 + q;
        A16[r*ASTR + col] = bf16of(acc[rt][ci][q]);
      }
    }
  }
  __syncthreads();
  #pragma unroll
  for (int i=0;i<2;++i){
    int id = t + (i<<8);
    int j = id>>7, c = id&127;
    float v = __uint_as_float(((unsigned)A16[(j*MC)*ASTR + c]) << 16);
    gate[j*C + c] = silu(v);
  }
  __syncthreads();
  for (int q=t; q<76*64; q+=256){
    int r = q>>6;
    int c2 = (q&63)*2;
    int j = r/MC;
    unsigned u = *(unsigned*)&A16[r*ASTR + c2];
    float2 f = bf2f2(u);
    f.x *= gate[j*C + c2];
    f.y *= gate[j*C + c2 + 1];
    *(unsigned*)&A16[r*ASTR + c2] = pack2(f.x, f.y);
  }
  __syncthreads();
  #pragma unroll
  for (int rt=0;rt<5;rt++)
    #pragma unroll
    for (int ci=0;ci<2;ci++){ acc[rt][ci][0]=0.f; acc[rt][ci][1]=0.f; acc[rt][ci][2]=0.f; acc[rt][ci][3]=0.f; }
  #pragma unroll
  for (int ks=0; ks<4; ++ks){
    int k0 = ks*32 + lg*8;
    const unsigned short* Ab = &A16[lr*ASTR + k0];
    bf16x8 a0 = *(const bf16x8*)(Ab);
    bf16x8 a1 = *(const bf16x8*)(Ab + 16*ASTR);
    bf16x8 a2 = *(const bf16x8*)(Ab + 32*ASTR);
    bf16x8 a3 = *(const bf16x8*)(Ab + 48*ASTR);
    bf16x8 a4 = *(const bf16x8*)(Ab + 64*ASTR);
    const unsigned short* Bb = &w2t[(colb + lr)*C + k0];
    bf16x8 b0 = *(const bf16x8*)(Bb);
    bf16x8 b1 = *(const bf16x8*)(Bb + 16*C);
    acc[0][0] = __builtin_amdgcn_mfma_f32_16x16x32_bf16(a0, b0, acc[0][0], 0, 0, 0);
    acc[1][0] = __builtin_amdgcn_mfma_f32_16x16x32_bf16(a1, b0, acc[1][0], 0, 0, 0);
    acc[2][0] = __builtin_amdgcn_mfma_f32_16x16x32_bf16(a2, b0, acc[2][0], 0, 0, 0);
    acc[3][0] = __builtin_amdgcn_mfma_f32_16x16x32_bf16(a3, b0, acc[3][0], 0, 0, 0);
    acc[4][0] = __builtin_amdgcn_mfma_f32_16x16x32_bf16(a4, b0, acc[4][0], 0, 0, 0);
    acc[0][1] = __builtin_amdgcn_mfma_f32_16x16x32_bf16(a0, b1, acc[0][1], 0, 0, 0);
    acc[1][1] = __builtin_amdgcn_mfma_f32_16x16x32_bf16(a1, b1, acc[1][1], 0, 0, 0);
    acc[2][1] = __builtin_amdgcn_mfma_f32_16x16x32_bf16(a2, b1, acc[2][1], 0, 0, 0);
    acc[3][1] = __builtin_amdgcn_mfma_f32_16x16x32_bf16(a3, b1, acc[3][1], 0, 0, 0);
    acc[4][1] = __builtin_amdgcn_mfma_f32_16x16x32_bf16(a4, b1, acc[4][1], 0, 0, 0);
  }
  #pragma unroll
  for (int rt=0;rt<5;rt++){
    #pragma unroll
    for (int ci=0;ci<2;ci++){
      int col = colb + 16*ci + lr;
      #pragma unroll
      for (int q=0;q<4;q++){
        int r = 16*rt + lg*4 + q;
        if (r < 4*MC){
          size_t off = ((size_t)(n0*MC + r))*C + col;
          x[off] += acc[rt][ci][q];
        }
      }
    }
  }
}

// ---------------- final head ----------------
__global__ __launch_bounds__(128) void k_final(const float* x, const float* nsf, const float* Wef1,
        const float* Wef2, const int* batch, float* out){
  __shared__ float sl[C];
  __shared__ float red[2];
  __shared__ float red2[2];
  int n = blockIdx.x; int t = threadIdx.x;
  float v = x[(size_t)n*MC*C + t];
  float sq = v*v;
  for (int d=32; d>0; d>>=1) sq += __shfl_down(sq, d, 64);
  if ((t&63)==0) red[t>>6] = sq;
  __syncthreads();
  float ms = (red[0]+red[1]) * (1.0f/128.f);
  float inv = 1.0f/sqrtf(ms + 1e-8f);
  sl[t] = v*inv*nsf[t];
  __syncthreads();
  float acc = 0.f;
  for (int cc=0; cc<C; ++cc) acc += sl[cc]*Wef1[cc*C + t];
  float val = acc*silu(acc)*Wef2[t];
  for (int d=32; d>0; d>>=1) val += __shfl_down(val, d, 64);
  if ((t&63)==0) red2[t>>6] = val;
  __syncthreads();
  if (t==0){
    float ne = red2[0]+red2[1];
    atomicAdd(&out[batch[n]], ne * (1.0f/77.81317f));
  }
}

extern "C" void kernel_launch(void* const* d_in, const int* in_sizes, int n_in,
                              void* d_out, int out_size, void* d_ws, size_t ws_size,
                              hipStream_t stream){
  (void)in_sizes; (void)n_in; (void)ws_size;
  const int*   anum  = (const int*)d_in[0];
  const int*   eidx  = (const int*)d_in[1];
  const float* dist  = (const float*)d_in[2];
  const int*   batch = (const int*)d_in[3];
  const float* emb   = (const float*)d_in[4];
  const float* We1   = (const float*)d_in[5];
  const float* We2   = (const float*)d_in[6];
  const float* Wdeg  = (const float*)d_in[7];
  const float* ns1   = (const float*)d_in[8];
  const float* ns2   = (const float*)d_in[9];
  const float* Wq    = (const float*)d_in[10];
  const float* Wk    = (const float*)d_in[11];
  const float* alpha = (const float*)d_in[12];
  const float* Wv    = (const float*)d_in[13];
  const float* Wrad  = (const float*)d_in[14];
  const float* Wo    = (const float*)d_in[15];
  const float* W1    = (const float*)d_in[16];
  const float* W2    = (const float*)d_in[17];
  const float* nsf   = (const float*)d_in[18];
  const float* Wef1  = (const float*)d_in[19];
  const float* Wef2  = (const float*)d_in[20];
  float* out = (float*)d_out;

  const int* srcarr = eidx;
  const int* tgtarr = eidx + N_EDGES;

  char* wsb = (char*)d_ws;
  unsigned short* efeat16 = (unsigned short*)wsb; wsb += (size_t)(NRADB*EB)*C*2;  // bf16, padded
  float* efsumT= (float*)wsb;  wsb += (size_t)N_NODES*C*4;
  float* x     = (float*)wsb;  wsb += (size_t)N_NODES*MC*C*4;
  unsigned char* Vb = (unsigned char*)wsb; wsb += (size_t)N_NODES*MC*C;    // fp8
  unsigned short* qb = (unsigned short*)wsb; wsb += (size_t)N_NODES*512*2;
  unsigned short* kb = (unsigned short*)wsb; wsb += (size_t)N_NODES*512*2;
  float* attnb = (float*)wsb;  wsb += (size_t)N_EDGES*8*4;
  float* radb  = (float*)wsb;  wsb += (size_t)N_EDGES*RSTR*4;
  int* deg     = (int*)wsb;    wsb += (size_t)N4*4;
  int* rowptr  = (int*)wsb;    wsb += (size_t)(N4+1)*4;
  int* cursor  = (int*)wsb;    wsb += (size_t)N4*4;
  int* elist   = (int*)wsb;    wsb += (size_t)N_EDGES*4;
  int2* epair  = (int2*)wsb;   wsb += (size_t)N_EDGES*8;
  unsigned short* we2t = (unsigned short*)wsb; wsb += (size_t)16384*2;
  unsigned short* wvt  = (unsigned short*)wsb; wsb += (size_t)4*16384*2;
  unsigned short* wot  = (unsigned short*)wsb; wsb += (size_t)4*16384*2;
  unsigned short* w1t  = (unsigned short*)wsb; wsb += (size_t)4*16384*2;
  unsigned short* w2t  = (unsigned short*)wsb; wsb += (size_t)4*16384*2;
  unsigned short* wqt  = (unsigned short*)wsb; wsb += (size_t)4*65536*2;
  unsigned short* wkt  = (unsigned short*)wsb; wsb += (size_t)4*65536*2;
  unsigned short* we1b = (unsigned short*)wsb; wsb += (size_t)NB*C*2;

  (void)hipMemsetAsync(deg, 0, N4*4, stream);
  (void)hipMemsetAsync(cursor, 0, N4*4, stream);
  (void)hipMemsetAsync(d_out, 0, (size_t)out_size*sizeof(float), stream);

  k_packall<<<1718, 256, 0, stream>>>(We2, Wv, Wo, W1, W2, Wq, Wk, We1,
                                      we2t, wvt, wot, w1t, w2t, wqt, wkt, we1b);
  k_count<<<(N_EDGES+255)/256, 256, 0, stream>>>(tgtarr, srcarr, deg);
  k_scan<<<1, 1024, 0, stream>>>(deg, rowptr);
  k_fill<<<(N_EDGES+255)/256, 256, 0, stream>>>(tgtarr, srcarr, rowptr, cursor, elist, epair);
  k_efeat<<<NRADB, 256, 0, stream>>>(dist, we1b, we2t, efeat16);
  k_efsum<<<N_NODES, 128, 0, stream>>>(efeat16, rowptr, elist, efsumT);
  k_deginit<<<dim3((N_NODES+15)/16, 5), 256, 0, stream>>>(efsumT, Wdeg, emb, anum, x);

  for (int i=0;i<NL;i++){
    k_nAqk<<<N_NODES/4 + NQKB*8, 256, 0, stream>>>(x, ns1 + i*5*C,
                                                   wvt + (size_t)i*16384,
                                                   wqt + (size_t)i*65536, wkt + (size_t)i*65536,
                                                   Vb, qb, kb);
    k_attnrad<<<N_NODES/4 + NRADB, 256, 0, stream>>>(qb, kb, alpha + i*512, rowptr, epair, attnb,
                                                     efeat16, Wrad + i*C*MC, radb);
    k_e1<<<N_NODES, 256, 0, stream>>>(Vb, radb, attnb, wot + (size_t)i*16384,
                                      rowptr, epair, x);
    k_nodeB<<<N_NODES/4, 256, 0, stream>>>(x, ns2 + i*5*C, w1t + (size_t)i*16384, w2t + (size_t)i*16384);
  }
  k_final<<<N_NODES, 128, 0, stream>>>(x, nsf, Wef1, Wef2, batch, out);
}